// Round 3
// baseline (3045.599 us; speedup 1.0000x reference)
//
#include <hip/hip_runtime.h>

// MessagePassingLayer, Round 3: LDS-tiled f32 wave-GEMM.
// Round-2 post-mortem: VGPR_Count=64 with 128+ live accumulator floats =>
// compiler demoted hid[]/msg[] to scratch; 40 RMW rounds x 64ch x 4B x 1.6M
// edges ~= 11.4 GB of scratch HBM writes (both rounds' real bottleneck).
// Fix: 16 accumulators/thread. Tile 64 edges/block in LDS (row stride 161,
// mod 32 == 1 -> conflict-free column reads); thread (lane,wave) computes
// channels [wave*16, wave*16+16) of edge `lane`; weights are wave-uniform ->
// scalar loads. relu(hid) tile reuses X LDS between layers.

#define HID 64
#define SCAN_CHUNK 1024
#define TE 64          // edges per block tile
#define SX 161         // LDS row stride (dwords), edge kernel: 160 cols + 1 pad
#define SXN 129        // LDS row stride, node kernel: 128 cols + 1 pad

// ---------------- CSR build ----------------
__global__ void hist_deg(const int* __restrict__ ei, int* __restrict__ deg, int E) {
  for (long long e = (long long)blockIdx.x * blockDim.x + threadIdx.x; e < E;
       e += (long long)gridDim.x * blockDim.x) {
    atomicAdd(&deg[ei[E + e]], 1);
  }
}

__global__ void scan_chunks(const int* __restrict__ deg, int* __restrict__ start,
                            int* __restrict__ chunk_sums, int N) {
  __shared__ int sdata[256];
  const int tid = threadIdx.x;
  const int base = blockIdx.x * SCAN_CHUNK + tid * 4;
  int v[4];
  int sum = 0;
#pragma unroll
  for (int k = 0; k < 4; ++k) {
    v[k] = (base + k < N) ? deg[base + k] : 0;
    sum += v[k];
  }
  sdata[tid] = sum;
  __syncthreads();
  for (int off = 1; off < 256; off <<= 1) {
    int t = (tid >= off) ? sdata[tid - off] : 0;
    __syncthreads();
    sdata[tid] += t;
    __syncthreads();
  }
  int run = (tid == 0) ? 0 : sdata[tid - 1];
#pragma unroll
  for (int k = 0; k < 4; ++k) {
    if (base + k < N) start[base + k] = run;
    run += v[k];
  }
  if (tid == 255) chunk_sums[blockIdx.x] = sdata[255];
}

__global__ void scan_sums(const int* __restrict__ chunk_sums, int* __restrict__ chunk_offs,
                          int nchunks) {
  __shared__ int s[1024];
  const int tid = threadIdx.x;
  for (int i = tid; i < nchunks; i += blockDim.x) s[i] = chunk_sums[i];
  __syncthreads();
  if (tid == 0) {
    int run = 0;
    for (int i = 0; i < nchunks; ++i) { int v = s[i]; s[i] = run; run += v; }
  }
  __syncthreads();
  for (int i = tid; i < nchunks; i += blockDim.x) chunk_offs[i] = s[i];
}

__global__ void add_offsets(int* __restrict__ start, const int* __restrict__ chunk_offs,
                            int* __restrict__ cursor, int N) {
  const int i = blockIdx.x * blockDim.x + threadIdx.x;
  if (i < N) {
    const int sgl = start[i] + chunk_offs[i / SCAN_CHUNK];
    start[i] = sgl;
    cursor[i] = sgl;
  }
}

__global__ void fill_elist(const int* __restrict__ ei, int* __restrict__ cursor,
                           int* __restrict__ elist, int E) {
  for (long long e = (long long)blockIdx.x * blockDim.x + threadIdx.x; e < E;
       e += (long long)gridDim.x * blockDim.x) {
    const int t = ei[E + e];
    const int pos = atomicAdd(&cursor[t], 1);
    elist[pos] = (int)e;
  }
}

// ---------------- tiled edge MLP ----------------
__global__ __launch_bounds__(256, 4)
void edge_mlp_tiled(const float* __restrict__ h, const int* __restrict__ ei,
                    const float* __restrict__ ef,
                    const float* __restrict__ W1, const float* __restrict__ b1,
                    const float* __restrict__ W2, const float* __restrict__ b2,
                    const int* __restrict__ elist, float* __restrict__ msgbuf, int E) {
  __shared__ float X[TE * SX];   // 64 x 161 f32 = 41.2 KB

  const int tid = threadIdx.x;
  const int wave = tid >> 6;
  const int lane = tid & 63;
  const long long base = (long long)blockIdx.x * TE;

  // ---- stage: thread (et, q) loads 40 floats of edge et's input row ----
  {
    const int et = tid >> 2;
    const int q = tid & 3;
    long long p = base + et;
    if (p >= E) p = E - 1;
    const int e = elist[p];
    const int src = ei[e];
    const int tgt = ei[E + e];

    const float4* rs = (const float4*)(h + (size_t)src * 64);
    const float4* rt = (const float4*)(h + (size_t)tgt * 64);
    const float4* re = (const float4*)(ef + (size_t)e * 32);
    float* row = &X[et * SX];
#pragma unroll
    for (int i = 0; i < 4; ++i) {
      const float4 v = rs[q * 4 + i];
      float* d = row + q * 16 + 4 * i;
      d[0] = v.x; d[1] = v.y; d[2] = v.z; d[3] = v.w;
    }
#pragma unroll
    for (int i = 0; i < 4; ++i) {
      const float4 v = rt[q * 4 + i];
      float* d = row + 64 + q * 16 + 4 * i;
      d[0] = v.x; d[1] = v.y; d[2] = v.z; d[3] = v.w;
    }
#pragma unroll
    for (int i = 0; i < 2; ++i) {
      const float4 v = re[q * 2 + i];
      float* d = row + 128 + q * 8 + 4 * i;
      d[0] = v.x; d[1] = v.y; d[2] = v.z; d[3] = v.w;
    }
  }
  __syncthreads();

  // ---- layer 1: thread computes channels [cb, cb+16) of edge `lane` ----
  const int cb = wave * 16;
  float acc[16];
#pragma unroll
  for (int c = 0; c < 16; ++c) acc[c] = b1[cb + c];

  const float* xrow = &X[lane * SX];
#pragma unroll 4
  for (int k = 0; k < 160; ++k) {
    const float xv = xrow[k];
    const float* __restrict__ wr = W1 + (size_t)k * 64 + cb;
#pragma unroll
    for (int c = 0; c < 16; ++c) acc[c] = fmaf(xv, wr[c], acc[c]);
  }
  __syncthreads();   // all layer-1 reads of X done

  // ---- relu(hid) back into X[. ][0..63] ----
  {
    float* arow = &X[lane * SX + cb];
#pragma unroll
    for (int c = 0; c < 16; ++c) arow[c] = fmaxf(acc[c], 0.0f);
  }
  __syncthreads();

  // ---- layer 2 ----
  float acc2[16];
#pragma unroll
  for (int c = 0; c < 16; ++c) acc2[c] = b2[cb + c];
#pragma unroll 4
  for (int k = 0; k < 64; ++k) {
    const float xv = xrow[k];
    const float* __restrict__ wr = W2 + (size_t)k * 64 + cb;
#pragma unroll
    for (int c = 0; c < 16; ++c) acc2[c] = fmaf(xv, wr[c], acc2[c]);
  }

  // ---- store msg (CSR position order) ----
  const long long p = base + lane;
  if (p < E) {
    float4* dst = (float4*)(msgbuf + (size_t)p * 64 + cb);
#pragma unroll
    for (int i = 0; i < 4; ++i)
      dst[i] = make_float4(acc2[4 * i], acc2[4 * i + 1], acc2[4 * i + 2], acc2[4 * i + 3]);
  }
}

// ---------------- gather ----------------
__global__ __launch_bounds__(256)
void gather_agg(const float* __restrict__ msgbuf, const int* __restrict__ start,
                const int* __restrict__ deg, float* __restrict__ agg, int N) {
  const int n = blockIdx.x * 4 + (threadIdx.x >> 6);
  const int lane = threadIdx.x & 63;
  if (n >= N) return;
  const int s = start[n];
  const int d = deg[n];
  const float* __restrict__ base = msgbuf + (size_t)s * 64 + lane;
  float a0 = 0.f, a1 = 0.f, a2 = 0.f, a3 = 0.f;
  int i = 0;
  for (; i + 4 <= d; i += 4) {
    a0 += base[(size_t)(i + 0) * 64];
    a1 += base[(size_t)(i + 1) * 64];
    a2 += base[(size_t)(i + 2) * 64];
    a3 += base[(size_t)(i + 3) * 64];
  }
  for (; i < d; ++i) a0 += base[(size_t)i * 64];
  agg[(size_t)n * 64 + lane] = (a0 + a1) + (a2 + a3);
}

// ---------------- tiled node MLP ----------------
__global__ __launch_bounds__(256, 4)
void node_mlp_tiled(const float* __restrict__ h, const float* __restrict__ agg,
                    const float* __restrict__ W1, const float* __restrict__ b1,
                    const float* __restrict__ W2, const float* __restrict__ b2,
                    float* __restrict__ out, int N) {
  __shared__ float X[TE * SXN];  // 64 x 129 f32 = 33 KB

  const int tid = threadIdx.x;
  const int wave = tid >> 6;
  const int lane = tid & 63;
  const long long base = (long long)blockIdx.x * TE;

  {
    const int nt = tid >> 2;
    const int q = tid & 3;
    long long n = base + nt;
    if (n >= N) n = N - 1;
    const float4* rh = (const float4*)(h + (size_t)n * 64);
    const float4* ra = (const float4*)(agg + (size_t)n * 64);
    float* row = &X[nt * SXN];
#pragma unroll
    for (int i = 0; i < 4; ++i) {
      const float4 v = rh[q * 4 + i];
      float* d = row + q * 16 + 4 * i;
      d[0] = v.x; d[1] = v.y; d[2] = v.z; d[3] = v.w;
    }
#pragma unroll
    for (int i = 0; i < 4; ++i) {
      const float4 v = ra[q * 4 + i];
      float* d = row + 64 + q * 16 + 4 * i;
      d[0] = v.x; d[1] = v.y; d[2] = v.z; d[3] = v.w;
    }
  }
  __syncthreads();

  const int cb = wave * 16;
  float acc[16];
#pragma unroll
  for (int c = 0; c < 16; ++c) acc[c] = b1[cb + c];

  const float* xrow = &X[lane * SXN];
#pragma unroll 4
  for (int k = 0; k < 128; ++k) {
    const float xv = xrow[k];
    const float* __restrict__ wr = W1 + (size_t)k * 64 + cb;
#pragma unroll
    for (int c = 0; c < 16; ++c) acc[c] = fmaf(xv, wr[c], acc[c]);
  }
  __syncthreads();

  {
    float* arow = &X[lane * SXN + cb];
#pragma unroll
    for (int c = 0; c < 16; ++c) arow[c] = fmaxf(acc[c], 0.0f);
  }
  __syncthreads();

  float acc2[16];
#pragma unroll
  for (int c = 0; c < 16; ++c) acc2[c] = b2[cb + c];
#pragma unroll 4
  for (int k = 0; k < 64; ++k) {
    const float xv = xrow[k];
    const float* __restrict__ wr = W2 + (size_t)k * 64 + cb;
#pragma unroll
    for (int c = 0; c < 16; ++c) acc2[c] = fmaf(xv, wr[c], acc2[c]);
  }

  const long long n = base + lane;
  if (n < N) {
    float4* dst = (float4*)(out + (size_t)n * 64 + cb);
#pragma unroll
    for (int i = 0; i < 4; ++i)
      dst[i] = make_float4(acc2[4 * i], acc2[4 * i + 1], acc2[4 * i + 2], acc2[4 * i + 3]);
  }
}

// ---------------- round-1 fallback (atomic scatter, only if ws too small) ----------------
__device__ __forceinline__ void fma_row4(float* __restrict__ hid, const float4 x,
                                         const float* __restrict__ w) {
#pragma unroll
  for (int j = 0; j < HID; ++j) {
    float t = fmaf(x.x, w[j], hid[j]);
    t = fmaf(x.y, w[64 + j], t);
    t = fmaf(x.z, w[128 + j], t);
    t = fmaf(x.w, w[192 + j], t);
    hid[j] = t;
  }
}

__global__ __launch_bounds__(256, 2)
void edge_mlp_scatter(const float* __restrict__ h, const int* __restrict__ ei,
                      const float* __restrict__ ef,
                      const float* __restrict__ W1, const float* __restrict__ b1,
                      const float* __restrict__ W2, const float* __restrict__ b2,
                      float* __restrict__ agg, int E) {
  const long long eg = (long long)blockIdx.x * 256 + threadIdx.x;
  const int e = (eg < E) ? (int)eg : 0;
  const int src = ei[e];
  const int tgt = ei[E + e];
  float hid[HID];
#pragma unroll
  for (int j = 0; j < HID; ++j) hid[j] = b1[j];
  const float4* xs = (const float4*)(h + (size_t)src * 64);
#pragma unroll 2
  for (int kk = 0; kk < 16; ++kk) fma_row4(hid, xs[kk], W1 + (size_t)(kk * 4) * 64);
  const float4* xt = (const float4*)(h + (size_t)tgt * 64);
#pragma unroll 2
  for (int kk = 0; kk < 16; ++kk) fma_row4(hid, xt[kk], W1 + (size_t)(64 + kk * 4) * 64);
  const float4* xe = (const float4*)(ef + (size_t)e * 32);
#pragma unroll 2
  for (int kk = 0; kk < 8; ++kk) fma_row4(hid, xe[kk], W1 + (size_t)(128 + kk * 4) * 64);
  float msg[HID];
#pragma unroll
  for (int j = 0; j < HID; ++j) msg[j] = b2[j];
#pragma unroll 2
  for (int k = 0; k < HID; ++k) {
    const float av = fmaxf(hid[k], 0.0f);
    const float* w = W2 + (size_t)k * 64;
#pragma unroll
    for (int j = 0; j < HID; ++j) msg[j] = fmaf(av, w[j], msg[j]);
  }
  if (eg < E) {
#pragma unroll
    for (int j = 0; j < HID; ++j) atomicAdd(agg + (size_t)tgt * 64 + j, msg[j]);
  }
}

__global__ __launch_bounds__(256, 2)
void node_update_fallback(const float* __restrict__ h, const float* __restrict__ agg,
                          const float* __restrict__ W1, const float* __restrict__ b1,
                          const float* __restrict__ W2, const float* __restrict__ b2,
                          float* __restrict__ out, int N) {
  const long long ng = (long long)blockIdx.x * blockDim.x + threadIdx.x;
  const bool valid = ng < N;
  const int n = valid ? (int)ng : 0;
  float hid[HID];
#pragma unroll
  for (int j = 0; j < HID; ++j) hid[j] = b1[j];
  const float4* xh = (const float4*)(h + (size_t)n * 64);
#pragma unroll 2
  for (int kk = 0; kk < 16; ++kk) fma_row4(hid, xh[kk], W1 + (size_t)(kk * 4) * 64);
  const float4* xa = (const float4*)(agg + (size_t)n * 64);
#pragma unroll 2
  for (int kk = 0; kk < 16; ++kk) fma_row4(hid, xa[kk], W1 + (size_t)(64 + kk * 4) * 64);
  float o[HID];
#pragma unroll
  for (int j = 0; j < HID; ++j) o[j] = b2[j];
#pragma unroll 2
  for (int k = 0; k < HID; ++k) {
    const float av = fmaxf(hid[k], 0.0f);
    const float* w = W2 + (size_t)k * 64;
#pragma unroll
    for (int j = 0; j < HID; ++j) o[j] = fmaf(av, w[j], o[j]);
  }
  if (valid) {
    float4* po = (float4*)(out + (size_t)n * 64);
#pragma unroll
    for (int j4 = 0; j4 < 16; ++j4)
      po[j4] = make_float4(o[4 * j4], o[4 * j4 + 1], o[4 * j4 + 2], o[4 * j4 + 3]);
  }
}

// ---------------- host ----------------
extern "C" void kernel_launch(void* const* d_in, const int* in_sizes, int n_in,
                              void* d_out, int out_size, void* d_ws, size_t ws_size,
                              hipStream_t stream) {
  const float* h   = (const float*)d_in[0];
  const int*   ei  = (const int*)d_in[1];
  const float* ef  = (const float*)d_in[2];
  const float* eW1 = (const float*)d_in[3];
  const float* eb1 = (const float*)d_in[4];
  const float* eW2 = (const float*)d_in[5];
  const float* eb2 = (const float*)d_in[6];
  const float* uW1 = (const float*)d_in[7];
  const float* ub1 = (const float*)d_in[8];
  const float* uW2 = (const float*)d_in[9];
  const float* ub2 = (const float*)d_in[10];
  float* out = (float*)d_out;

  const int N = in_sizes[0] / 64;   // 100000
  const int E = in_sizes[1] / 2;    // 1600000
  const int nchunks = (N + SCAN_CHUNK - 1) / SCAN_CHUNK;

  size_t off = 0;
  auto alloc = [&](size_t bytes) { size_t o = off; off += (bytes + 255) & ~(size_t)255; return o; };
  const size_t msg_off    = alloc((size_t)E * 64 * sizeof(float));   // 409.6 MB
  const size_t agg_off    = alloc((size_t)N * 64 * sizeof(float));   // 25.6 MB
  const size_t elist_off  = alloc((size_t)E * sizeof(int));          // 6.4 MB
  const size_t deg_off    = alloc((size_t)N * sizeof(int));
  const size_t start_off  = alloc((size_t)N * sizeof(int));
  const size_t cursor_off = alloc((size_t)N * sizeof(int));
  const size_t csum_off   = alloc((size_t)nchunks * sizeof(int));
  const size_t coff_off   = alloc((size_t)nchunks * sizeof(int));
  char* ws = (char*)d_ws;

  if (ws_size >= off) {
    float* msg   = (float*)(ws + msg_off);
    float* agg   = (float*)(ws + agg_off);
    int* elist   = (int*)(ws + elist_off);
    int* deg     = (int*)(ws + deg_off);
    int* start   = (int*)(ws + start_off);
    int* cursor  = (int*)(ws + cursor_off);
    int* csum    = (int*)(ws + csum_off);
    int* coff    = (int*)(ws + coff_off);

    hipMemsetAsync(deg, 0, (size_t)N * sizeof(int), stream);
    hist_deg<<<1024, 256, 0, stream>>>(ei, deg, E);
    scan_chunks<<<nchunks, 256, 0, stream>>>(deg, start, csum, N);
    scan_sums<<<1, 256, 0, stream>>>(csum, coff, nchunks);
    add_offsets<<<(N + 255) / 256, 256, 0, stream>>>(start, coff, cursor, N);
    fill_elist<<<1024, 256, 0, stream>>>(ei, cursor, elist, E);
    edge_mlp_tiled<<<(E + TE - 1) / TE, 256, 0, stream>>>(h, ei, ef, eW1, eb1, eW2, eb2, elist, msg, E);
    gather_agg<<<(N + 3) / 4, 256, 0, stream>>>(msg, start, deg, agg, N);
    node_mlp_tiled<<<(N + TE - 1) / TE, 256, 0, stream>>>(h, agg, uW1, ub1, uW2, ub2, out, N);
  } else {
    float* agg = (float*)d_ws;
    hipMemsetAsync(agg, 0, (size_t)N * 64 * sizeof(float), stream);
    edge_mlp_scatter<<<(E + 255) / 256, 256, 0, stream>>>(h, ei, ef, eW1, eb1, eW2, eb2, agg, E);
    node_update_fallback<<<(N + 255) / 256, 256, 0, stream>>>(h, agg, uW1, ub1, uW2, ub2, out, N);
  }
}

// Round 4
// 476.896 us; speedup vs baseline: 6.3863x; 6.3863x over previous
//
#include <hip/hip_runtime.h>

// MessagePassingLayer, Round 4: bf16 MFMA edge/node MLPs + CSR gather.
// R3 post-mortem: f32 path latency-bound on per-lane weight streaming
// (3584 broadcast global loads/thread); VALU floor alone is ~300us. Harness
// threshold is bf16-floor (0.103) -> bf16 MFMA is in-spec. mfma_f32_16x16x32_bf16,
// 64-edge tiles, X staged bf16 in LDS, weights pre-packed into B-fragment order
// (7x16B loads/wave), msgbuf in bf16. Compute floor ~23us; pipeline ~memory-bound.

typedef __attribute__((ext_vector_type(8))) short s16x8;     // MFMA A/B frag (8 bf16)
typedef __attribute__((ext_vector_type(4))) float f32x4;     // MFMA C/D frag
typedef __attribute__((ext_vector_type(8))) unsigned short u16x8;

#define SCAN_CHUNK 1024
#define SXE 168   // edge X tile row stride (bf16): 160 cols + 8 pad; 336B rows, 16B-aligned
#define SXN 136   // node X tile row stride: 128 + 8 pad
#define SX2 72    // layer-2 activation tile stride: 64 + 8 pad

__device__ __forceinline__ unsigned short f2bf(float f) {   // RNE f32->bf16
  unsigned int u = __builtin_bit_cast(unsigned int, f);
  u += 0x7fffu + ((u >> 16) & 1u);
  return (unsigned short)(u >> 16);
}
__device__ __forceinline__ float bf2f(unsigned short s) {
  unsigned int u = ((unsigned int)s) << 16;
  return __builtin_bit_cast(float, u);
}
__device__ __forceinline__ u16x8 pack8(const float4 a, const float4 b) {
  u16x8 r;
  r[0] = f2bf(a.x); r[1] = f2bf(a.y); r[2] = f2bf(a.z); r[3] = f2bf(a.w);
  r[4] = f2bf(b.x); r[5] = f2bf(b.y); r[6] = f2bf(b.z); r[7] = f2bf(b.w);
  return r;
}

// ---------------- pre-pass: conversions / weight packing ----------------
__global__ void conv_bf16(const float* __restrict__ src, unsigned short* __restrict__ dst,
                          long long total) {
  const long long i = ((long long)blockIdx.x * blockDim.x + threadIdx.x) * 4;
  if (i + 3 < total) {
    const float4 v = *(const float4*)(src + i);
    ushort4 o;
    o.x = f2bf(v.x); o.y = f2bf(v.y); o.z = f2bf(v.z); o.w = f2bf(v.w);
    *(ushort4*)(dst + i) = o;
  } else {
    for (long long j = i; j < total; ++j) dst[j] = f2bf(src[j]);
  }
}

// Pack W[K][64] f32 -> frag order: dst[((kk*4+g)*64 + c)*8 + e] = bf16(W[kk*32+8g+e][c])
__global__ void pack_weights(const float* __restrict__ src, unsigned short* __restrict__ dst,
                             int K) {
  const int tid = blockIdx.x * blockDim.x + threadIdx.x;
  const int total = (K / 8) * 64;
  if (tid >= total) return;
  const int kkg = tid >> 6;   // k-octet index
  const int c = tid & 63;
#pragma unroll
  for (int e = 0; e < 8; ++e)
    dst[(size_t)tid * 8 + e] = f2bf(src[(size_t)(kkg * 8 + e) * 64 + c]);
}

// ---------------- CSR build ----------------
__global__ void hist_deg(const int* __restrict__ ei, int* __restrict__ deg, int E) {
  for (long long e = (long long)blockIdx.x * blockDim.x + threadIdx.x; e < E;
       e += (long long)gridDim.x * blockDim.x)
    atomicAdd(&deg[ei[E + e]], 1);
}

__global__ void scan_chunks(const int* __restrict__ deg, int* __restrict__ start,
                            int* __restrict__ chunk_sums, int N) {
  __shared__ int sdata[256];
  const int tid = threadIdx.x;
  const int base = blockIdx.x * SCAN_CHUNK + tid * 4;
  int v[4];
  int sum = 0;
#pragma unroll
  for (int k = 0; k < 4; ++k) {
    v[k] = (base + k < N) ? deg[base + k] : 0;
    sum += v[k];
  }
  sdata[tid] = sum;
  __syncthreads();
  for (int off = 1; off < 256; off <<= 1) {
    int t = (tid >= off) ? sdata[tid - off] : 0;
    __syncthreads();
    sdata[tid] += t;
    __syncthreads();
  }
  int run = (tid == 0) ? 0 : sdata[tid - 1];
#pragma unroll
  for (int k = 0; k < 4; ++k) {
    if (base + k < N) start[base + k] = run;
    run += v[k];
  }
  if (tid == 255) chunk_sums[blockIdx.x] = sdata[255];
}

__global__ void scan_sums(const int* __restrict__ chunk_sums, int* __restrict__ chunk_offs,
                          int nchunks) {
  __shared__ int s[1024];
  const int tid = threadIdx.x;
  for (int i = tid; i < nchunks; i += blockDim.x) s[i] = chunk_sums[i];
  __syncthreads();
  if (tid == 0) {
    int run = 0;
    for (int i = 0; i < nchunks; ++i) { int v = s[i]; s[i] = run; run += v; }
  }
  __syncthreads();
  for (int i = tid; i < nchunks; i += blockDim.x) chunk_offs[i] = s[i];
}

__global__ void add_offsets(int* __restrict__ start, const int* __restrict__ chunk_offs,
                            int* __restrict__ cursor, int N) {
  const int i = blockIdx.x * blockDim.x + threadIdx.x;
  if (i < N) {
    const int sgl = start[i] + chunk_offs[i / SCAN_CHUNK];
    start[i] = sgl;
    cursor[i] = sgl;
  }
}

__global__ void fill_elist(const int* __restrict__ ei, int* __restrict__ cursor,
                           int* __restrict__ elist, int E) {
  for (long long e = (long long)blockIdx.x * blockDim.x + threadIdx.x; e < E;
       e += (long long)gridDim.x * blockDim.x) {
    const int t = ei[E + e];
    const int pos = atomicAdd(&cursor[t], 1);
    elist[pos] = (int)e;
  }
}

// ---------------- edge MLP (MFMA) ----------------
// Fragment maps (mfma_f32_16x16x32_bf16, lane l: g=l>>4, r=l&15):
//   A[m][k]: m=r, k=8g+e   B[k][n]: n=r, k=8g+e   D[m][n]: n=r, m=4g+i
__global__ __launch_bounds__(256, 4)
void edge_mlp_mfma(const unsigned short* __restrict__ hb, const int* __restrict__ ei,
                   const float* __restrict__ ef,
                   const unsigned short* __restrict__ w1p, const float* __restrict__ b1,
                   const unsigned short* __restrict__ w2p, const float* __restrict__ b2,
                   const int* __restrict__ elist, unsigned short* __restrict__ msg, int E) {
  __shared__ unsigned short X[64 * SXE];    // 21.5 KB
  __shared__ unsigned short X2[64 * SX2];   // 9.2 KB

  const int tid = threadIdx.x;
  const int w = tid >> 6, lane = tid & 63;
  const int g = lane >> 4, r = lane & 15;
  const long long base = (long long)blockIdx.x * 64;

  // ---- stage X = [h[src] || h[tgt] || ef] as bf16; thread (row, q) loads 40 cols ----
  {
    const int row = tid >> 2, q = tid & 3;
    long long p = base + row;
    if (p >= E) p = E - 1;
    const int e = elist[p];
    const int src = ei[e], tgt = ei[E + e];
    const u16x8* hs = (const u16x8*)(hb + (size_t)src * 64);
    const u16x8* ht = (const u16x8*)(hb + (size_t)tgt * 64);
    *(u16x8*)&X[row * SXE + 16 * q] = hs[2 * q];
    *(u16x8*)&X[row * SXE + 16 * q + 8] = hs[2 * q + 1];
    *(u16x8*)&X[row * SXE + 64 + 16 * q] = ht[2 * q];
    *(u16x8*)&X[row * SXE + 64 + 16 * q + 8] = ht[2 * q + 1];
    const float4* fe = (const float4*)(ef + (size_t)e * 32);
    *(u16x8*)&X[row * SXE + 128 + 8 * q] = pack8(fe[2 * q], fe[2 * q + 1]);
  }
  __syncthreads();

  const int cb = w * 16;  // this wave's channel block

  // ---- layer 1: K=160 (5 MFMA k-steps), 4 row-tiles ----
  const float bias1 = b1[cb + r];
  f32x4 acc[4];
  acc[0] = acc[1] = acc[2] = acc[3] = (f32x4){bias1, bias1, bias1, bias1};
#pragma unroll
  for (int kk = 0; kk < 5; ++kk) {
    const s16x8 bf = *(const s16x8*)(w1p + (size_t)((kk * 4 + g) * 64 + cb + r) * 8);
#pragma unroll
    for (int er = 0; er < 4; ++er) {
      const s16x8 af = *(const s16x8*)&X[(er * 16 + r) * SXE + kk * 32 + 8 * g];
      acc[er] = __builtin_amdgcn_mfma_f32_16x16x32_bf16(af, bf, acc[er], 0, 0, 0);
    }
  }

  // ---- relu -> X2 (bf16) ----
#pragma unroll
  for (int er = 0; er < 4; ++er)
#pragma unroll
    for (int i = 0; i < 4; ++i)
      X2[(er * 16 + 4 * g + i) * SX2 + cb + r] = f2bf(fmaxf(acc[er][i], 0.0f));
  __syncthreads();

  // ---- layer 2: K=64 (2 k-steps) ----
  const float bias2 = b2[cb + r];
  f32x4 a2[4];
  a2[0] = a2[1] = a2[2] = a2[3] = (f32x4){bias2, bias2, bias2, bias2};
#pragma unroll
  for (int kk = 0; kk < 2; ++kk) {
    const s16x8 bf = *(const s16x8*)(w2p + (size_t)((kk * 4 + g) * 64 + cb + r) * 8);
#pragma unroll
    for (int er = 0; er < 4; ++er) {
      const s16x8 af = *(const s16x8*)&X2[(er * 16 + r) * SX2 + kk * 32 + 8 * g];
      a2[er] = __builtin_amdgcn_mfma_f32_16x16x32_bf16(af, bf, a2[er], 0, 0, 0);
    }
  }

  // ---- store msg (bf16, CSR position order) ----
#pragma unroll
  for (int er = 0; er < 4; ++er)
#pragma unroll
    for (int i = 0; i < 4; ++i) {
      const long long p = base + er * 16 + 4 * g + i;
      if (p < E) msg[p * 64 + cb + r] = f2bf(a2[er][i]);
    }
}

// ---------------- gather (bf16 msg -> f32 agg) ----------------
__global__ __launch_bounds__(256)
void gather_agg(const unsigned short* __restrict__ msg, const int* __restrict__ start,
                const int* __restrict__ deg, float* __restrict__ agg, int N) {
  const int n = blockIdx.x * 4 + (threadIdx.x >> 6);
  const int lane = threadIdx.x & 63;
  if (n >= N) return;
  const int s = start[n], d = deg[n];
  const unsigned short* b = msg + (size_t)s * 64 + lane;
  float a0 = 0.f, a1 = 0.f, a2 = 0.f, a3 = 0.f;
  int i = 0;
  for (; i + 4 <= d; i += 4) {
    a0 += bf2f(b[(size_t)(i + 0) * 64]);
    a1 += bf2f(b[(size_t)(i + 1) * 64]);
    a2 += bf2f(b[(size_t)(i + 2) * 64]);
    a3 += bf2f(b[(size_t)(i + 3) * 64]);
  }
  for (; i < d; ++i) a0 += bf2f(b[(size_t)i * 64]);
  agg[(size_t)n * 64 + lane] = (a0 + a1) + (a2 + a3);
}

// ---------------- node MLP (MFMA) ----------------
__global__ __launch_bounds__(256, 4)
void node_mlp_mfma(const unsigned short* __restrict__ hb, const float* __restrict__ agg,
                   const unsigned short* __restrict__ w1p, const float* __restrict__ b1,
                   const unsigned short* __restrict__ w2p, const float* __restrict__ b2,
                   float* __restrict__ out, int N) {
  __shared__ unsigned short X[64 * SXN];    // 17.4 KB
  __shared__ unsigned short X2[64 * SX2];   // 9.2 KB

  const int tid = threadIdx.x;
  const int w = tid >> 6, lane = tid & 63;
  const int g = lane >> 4, r = lane & 15;
  const long long base = (long long)blockIdx.x * 64;

  // ---- stage X = [h || agg] ----
  {
    const int row = tid >> 2, q = tid & 3;
    long long n = base + row;
    if (n >= N) n = N - 1;
    const u16x8* hr = (const u16x8*)(hb + (size_t)n * 64);
    *(u16x8*)&X[row * SXN + 16 * q] = hr[2 * q];
    *(u16x8*)&X[row * SXN + 16 * q + 8] = hr[2 * q + 1];
    const float4* ar = (const float4*)(agg + (size_t)n * 64);
    *(u16x8*)&X[row * SXN + 64 + 16 * q] = pack8(ar[4 * q], ar[4 * q + 1]);
    *(u16x8*)&X[row * SXN + 64 + 16 * q + 8] = pack8(ar[4 * q + 2], ar[4 * q + 3]);
  }
  __syncthreads();

  const int cb = w * 16;

  // ---- layer 1: K=128 (4 k-steps) ----
  const float bias1 = b1[cb + r];
  f32x4 acc[4];
  acc[0] = acc[1] = acc[2] = acc[3] = (f32x4){bias1, bias1, bias1, bias1};
#pragma unroll
  for (int kk = 0; kk < 4; ++kk) {
    const s16x8 bf = *(const s16x8*)(w1p + (size_t)((kk * 4 + g) * 64 + cb + r) * 8);
#pragma unroll
    for (int er = 0; er < 4; ++er) {
      const s16x8 af = *(const s16x8*)&X[(er * 16 + r) * SXN + kk * 32 + 8 * g];
      acc[er] = __builtin_amdgcn_mfma_f32_16x16x32_bf16(af, bf, acc[er], 0, 0, 0);
    }
  }

#pragma unroll
  for (int er = 0; er < 4; ++er)
#pragma unroll
    for (int i = 0; i < 4; ++i)
      X2[(er * 16 + 4 * g + i) * SX2 + cb + r] = f2bf(fmaxf(acc[er][i], 0.0f));
  __syncthreads();

  // ---- layer 2: K=64 ----
  const float bias2 = b2[cb + r];
  f32x4 a2[4];
  a2[0] = a2[1] = a2[2] = a2[3] = (f32x4){bias2, bias2, bias2, bias2};
#pragma unroll
  for (int kk = 0; kk < 2; ++kk) {
    const s16x8 bf = *(const s16x8*)(w2p + (size_t)((kk * 4 + g) * 64 + cb + r) * 8);
#pragma unroll
    for (int er = 0; er < 4; ++er) {
      const s16x8 af = *(const s16x8*)&X2[(er * 16 + r) * SX2 + kk * 32 + 8 * g];
      a2[er] = __builtin_amdgcn_mfma_f32_16x16x32_bf16(af, bf, a2[er], 0, 0, 0);
    }
  }

  // ---- store out (f32) ----
#pragma unroll
  for (int er = 0; er < 4; ++er)
#pragma unroll
    for (int i = 0; i < 4; ++i) {
      const long long n = base + er * 16 + 4 * g + i;
      if (n < N) out[n * 64 + cb + r] = a2[er][i];
    }
}

// ---------------- host ----------------
extern "C" void kernel_launch(void* const* d_in, const int* in_sizes, int n_in,
                              void* d_out, int out_size, void* d_ws, size_t ws_size,
                              hipStream_t stream) {
  const float* h   = (const float*)d_in[0];
  const int*   ei  = (const int*)d_in[1];
  const float* ef  = (const float*)d_in[2];
  const float* eW1 = (const float*)d_in[3];
  const float* eb1 = (const float*)d_in[4];
  const float* eW2 = (const float*)d_in[5];
  const float* eb2 = (const float*)d_in[6];
  const float* uW1 = (const float*)d_in[7];
  const float* ub1 = (const float*)d_in[8];
  const float* uW2 = (const float*)d_in[9];
  const float* ub2 = (const float*)d_in[10];
  float* out = (float*)d_out;

  const int N = in_sizes[0] / 64;   // 100000
  const int E = in_sizes[1] / 2;    // 1600000
  const int nchunks = (N + SCAN_CHUNK - 1) / SCAN_CHUNK;

  size_t off = 0;
  auto alloc = [&](size_t bytes) { size_t o = off; off += (bytes + 255) & ~(size_t)255; return o; };
  const size_t msg_off    = alloc((size_t)E * 64 * 2);        // 204.8 MB bf16
  const size_t agg_off    = alloc((size_t)N * 64 * 4);        // 25.6 MB f32
  const size_t hb_off     = alloc((size_t)N * 64 * 2);        // 12.8 MB bf16
  const size_t w1p_off    = alloc((size_t)160 * 64 * 2);
  const size_t w2p_off    = alloc((size_t)64 * 64 * 2);
  const size_t uw1p_off   = alloc((size_t)128 * 64 * 2);
  const size_t uw2p_off   = alloc((size_t)64 * 64 * 2);
  const size_t elist_off  = alloc((size_t)E * 4);
  const size_t deg_off    = alloc((size_t)N * 4);
  const size_t start_off  = alloc((size_t)N * 4);
  const size_t cursor_off = alloc((size_t)N * 4);
  const size_t csum_off   = alloc((size_t)nchunks * 4);
  const size_t coff_off   = alloc((size_t)nchunks * 4);
  char* ws = (char*)d_ws;

  unsigned short* msg  = (unsigned short*)(ws + msg_off);
  float*          agg  = (float*)(ws + agg_off);
  unsigned short* hb   = (unsigned short*)(ws + hb_off);
  unsigned short* w1p  = (unsigned short*)(ws + w1p_off);
  unsigned short* w2p  = (unsigned short*)(ws + w2p_off);
  unsigned short* uw1p = (unsigned short*)(ws + uw1p_off);
  unsigned short* uw2p = (unsigned short*)(ws + uw2p_off);
  int* elist  = (int*)(ws + elist_off);
  int* deg    = (int*)(ws + deg_off);
  int* start  = (int*)(ws + start_off);
  int* cursor = (int*)(ws + cursor_off);
  int* csum   = (int*)(ws + csum_off);
  int* coff   = (int*)(ws + coff_off);

  // pre-pass
  const long long htot = (long long)N * 64;
  conv_bf16<<<(int)((htot / 4 + 255) / 256), 256, 0, stream>>>(h, hb, htot);
  pack_weights<<<(160 / 8 * 64 + 255) / 256, 256, 0, stream>>>(eW1, w1p, 160);
  pack_weights<<<(64 / 8 * 64 + 255) / 256, 256, 0, stream>>>(eW2, w2p, 64);
  pack_weights<<<(128 / 8 * 64 + 255) / 256, 256, 0, stream>>>(uW1, uw1p, 128);
  pack_weights<<<(64 / 8 * 64 + 255) / 256, 256, 0, stream>>>(uW2, uw2p, 64);

  // CSR build
  hipMemsetAsync(deg, 0, (size_t)N * 4, stream);
  hist_deg<<<1024, 256, 0, stream>>>(ei, deg, E);
  scan_chunks<<<nchunks, 256, 0, stream>>>(deg, start, csum, N);
  scan_sums<<<1, 256, 0, stream>>>(csum, coff, nchunks);
  add_offsets<<<(N + 255) / 256, 256, 0, stream>>>(start, coff, cursor, N);
  fill_elist<<<1024, 256, 0, stream>>>(ei, cursor, elist, E);

  // main pipeline
  edge_mlp_mfma<<<(E + 63) / 64, 256, 0, stream>>>(hb, ei, ef, w1p, eb1, w2p, eb2, elist, msg, E);
  gather_agg<<<(N + 3) / 4, 256, 0, stream>>>(msg, start, deg, agg, N);
  node_mlp_mfma<<<(N + 63) / 64, 256, 0, stream>>>(hb, agg, uw1p, ub1, uw2p, ub2, out, N);
}

// Round 5
// 360.123 us; speedup vs baseline: 8.4571x; 1.3243x over previous
//
#include <hip/hip_runtime.h>

// MessagePassingLayer, Round 5: fused edge-MFMA + segmented atomic reduce.
// R4 post-mortem: edge kernel latency-bound (MfmaUtil 10%, HBM 39%) on a
// 3-deep random-load chain; msg round-trip (410 MB) was the largest traffic.
// Changes: (1) CSR order is tgt-sorted -> per-tile segmented reduction in LDS
// (reuse X2 as message tile), one f32 atomicAdd per run per channel (~51 MB)
// replaces msg write + gather kernel read (410 MB). (2) fill_elist emits
// planar esrc/etgt/eeid -> staging chain depth 2. (3) fewer launches.

typedef __attribute__((ext_vector_type(8))) short s16x8;     // MFMA A/B frag
typedef __attribute__((ext_vector_type(4))) float f32x4;     // MFMA C/D frag
typedef __attribute__((ext_vector_type(8))) unsigned short u16x8;

#define SCAN_CHUNK 1024
#define SXE 168   // edge X tile row stride (bf16)
#define SXN 136   // node X tile row stride
#define SX2 72    // activation/message tile stride

__device__ __forceinline__ unsigned short f2bf(float f) {   // RNE f32->bf16
  unsigned int u = __builtin_bit_cast(unsigned int, f);
  u += 0x7fffu + ((u >> 16) & 1u);
  return (unsigned short)(u >> 16);
}
__device__ __forceinline__ float bf2f(unsigned short s) {
  unsigned int u = ((unsigned int)s) << 16;
  return __builtin_bit_cast(float, u);
}
__device__ __forceinline__ u16x8 pack8(const float4 a, const float4 b) {
  u16x8 r;
  r[0] = f2bf(a.x); r[1] = f2bf(a.y); r[2] = f2bf(a.z); r[3] = f2bf(a.w);
  r[4] = f2bf(b.x); r[5] = f2bf(b.y); r[6] = f2bf(b.z); r[7] = f2bf(b.w);
  return r;
}

// ---------------- pre-pass ----------------
__global__ void conv_bf16(const float* __restrict__ src, unsigned short* __restrict__ dst,
                          long long total) {
  const long long i = ((long long)blockIdx.x * blockDim.x + threadIdx.x) * 4;
  if (i + 3 < total) {
    const float4 v = *(const float4*)(src + i);
    ushort4 o;
    o.x = f2bf(v.x); o.y = f2bf(v.y); o.z = f2bf(v.z); o.w = f2bf(v.w);
    *(ushort4*)(dst + i) = o;
  } else {
    for (long long j = i; j < total; ++j) dst[j] = f2bf(src[j]);
  }
}

// Pack all 4 weight matrices into fragment order in one launch.
// dst[(kg*64 + c)*8 + e] = bf16(src[(kg*8+e)*64 + c]); k-octets: eW1 20, eW2 8, uW1 16, uW2 8.
__global__ void pack_weights_all(const float* __restrict__ eW1, const float* __restrict__ eW2,
                                 const float* __restrict__ uW1, const float* __restrict__ uW2,
                                 unsigned short* __restrict__ w1p, unsigned short* __restrict__ w2p,
                                 unsigned short* __restrict__ uw1p, unsigned short* __restrict__ uw2p) {
  const int tid = blockIdx.x * blockDim.x + threadIdx.x;
  if (tid >= 52 * 64) return;
  const int c = tid & 63;
  int kg = tid >> 6;
  const float* src;
  unsigned short* dst;
  if (kg < 20)      { src = eW1; dst = w1p; }
  else if (kg < 28) { src = eW2; dst = w2p; kg -= 20; }
  else if (kg < 44) { src = uW1; dst = uw1p; kg -= 28; }
  else              { src = uW2; dst = uw2p; kg -= 44; }
#pragma unroll
  for (int e = 0; e < 8; ++e)
    dst[(size_t)(kg * 64 + c) * 8 + e] = f2bf(src[(size_t)(kg * 8 + e) * 64 + c]);
}

// ---------------- CSR build ----------------
__global__ void hist_deg(const int* __restrict__ ei, int* __restrict__ deg, int E) {
  for (long long e = (long long)blockIdx.x * blockDim.x + threadIdx.x; e < E;
       e += (long long)gridDim.x * blockDim.x)
    atomicAdd(&deg[ei[E + e]], 1);
}

__global__ void scan_chunks(const int* __restrict__ deg, int* __restrict__ start,
                            int* __restrict__ chunk_sums, int N) {
  __shared__ int sdata[256];
  const int tid = threadIdx.x;
  const int base = blockIdx.x * SCAN_CHUNK + tid * 4;
  int v[4];
  int sum = 0;
#pragma unroll
  for (int k = 0; k < 4; ++k) {
    v[k] = (base + k < N) ? deg[base + k] : 0;
    sum += v[k];
  }
  sdata[tid] = sum;
  __syncthreads();
  for (int off = 1; off < 256; off <<= 1) {
    int t = (tid >= off) ? sdata[tid - off] : 0;
    __syncthreads();
    sdata[tid] += t;
    __syncthreads();
  }
  int run = (tid == 0) ? 0 : sdata[tid - 1];
#pragma unroll
  for (int k = 0; k < 4; ++k) {
    if (base + k < N) start[base + k] = run;
    run += v[k];
  }
  if (tid == 255) chunk_sums[blockIdx.x] = sdata[255];
}

__global__ void scan_sums(const int* __restrict__ chunk_sums, int* __restrict__ chunk_offs,
                          int nchunks) {
  __shared__ int s[1024];
  const int tid = threadIdx.x;
  for (int i = tid; i < nchunks; i += blockDim.x) s[i] = chunk_sums[i];
  __syncthreads();
  if (tid == 0) {
    int run = 0;
    for (int i = 0; i < nchunks; ++i) { int v = s[i]; s[i] = run; run += v; }
  }
  __syncthreads();
  for (int i = tid; i < nchunks; i += blockDim.x) chunk_offs[i] = s[i];
}

__global__ void add_offsets(int* __restrict__ start, const int* __restrict__ chunk_offs,
                            int* __restrict__ cursor, int N) {
  const int i = blockIdx.x * blockDim.x + threadIdx.x;
  if (i < N) {
    const int sgl = start[i] + chunk_offs[i / SCAN_CHUNK];
    start[i] = sgl;
    cursor[i] = sgl;
  }
}

// planar fill: per CSR position, store src node, tgt node, edge id
__global__ void fill_elist(const int* __restrict__ ei, int* __restrict__ cursor,
                           int* __restrict__ esrc, int* __restrict__ etgt,
                           int* __restrict__ eeid, int E) {
  for (long long e = (long long)blockIdx.x * blockDim.x + threadIdx.x; e < E;
       e += (long long)gridDim.x * blockDim.x) {
    const int t = ei[E + e];
    const int s = ei[e];
    const int pos = atomicAdd(&cursor[t], 1);
    esrc[pos] = s;
    etgt[pos] = t;
    eeid[pos] = (int)e;
  }
}

// ---------------- fused edge MLP + segmented reduce ----------------
// Fragment maps (mfma_f32_16x16x32_bf16, lane l: g=l>>4, r=l&15):
//   A[m][k]: m=r, k=8g+e   B[k][n]: n=r, k=8g+e   D[m][n]: n=r, m=4g+i
__global__ __launch_bounds__(256, 4)
void edge_mlp_fused(const unsigned short* __restrict__ hb, const float* __restrict__ ef,
                    const unsigned short* __restrict__ w1p, const float* __restrict__ b1,
                    const unsigned short* __restrict__ w2p, const float* __restrict__ b2,
                    const int* __restrict__ esrc, const int* __restrict__ etgt,
                    const int* __restrict__ eeid, float* __restrict__ agg, int E) {
  __shared__ unsigned short X[64 * SXE];    // 21.5 KB input tile
  __shared__ unsigned short X2[64 * SX2];   // 9.2 KB: relu acts, then message tile
  __shared__ int tgts[64];

  const int tid = threadIdx.x;
  const int w = tid >> 6, lane = tid & 63;
  const int g = lane >> 4, r = lane & 15;
  const long long base = (long long)blockIdx.x * 64;

  // ---- stage: coalesced plane loads -> random 16B gathers (depth-2 chain) ----
  {
    const int row = tid >> 2, q = tid & 3;
    long long p = base + row;
    if (p >= E) p = E - 1;
    const int s = esrc[p];
    const int t = etgt[p];
    const int e = eeid[p];
    const u16x8* hs = (const u16x8*)(hb + (size_t)s * 64);
    const u16x8* ht = (const u16x8*)(hb + (size_t)t * 64);
    *(u16x8*)&X[row * SXE + 16 * q] = hs[2 * q];
    *(u16x8*)&X[row * SXE + 16 * q + 8] = hs[2 * q + 1];
    *(u16x8*)&X[row * SXE + 64 + 16 * q] = ht[2 * q];
    *(u16x8*)&X[row * SXE + 64 + 16 * q + 8] = ht[2 * q + 1];
    const float4* fe = (const float4*)(ef + (size_t)e * 32);
    *(u16x8*)&X[row * SXE + 128 + 8 * q] = pack8(fe[2 * q], fe[2 * q + 1]);
    if (q == 0) tgts[row] = (base + row < E) ? t : -1;
  }
  __syncthreads();

  const int cb = w * 16;

  // ---- layer 1: K=160 ----
  const float bias1 = b1[cb + r];
  f32x4 acc[4];
  acc[0] = acc[1] = acc[2] = acc[3] = (f32x4){bias1, bias1, bias1, bias1};
#pragma unroll
  for (int kk = 0; kk < 5; ++kk) {
    const s16x8 bf = *(const s16x8*)(w1p + (size_t)((kk * 4 + g) * 64 + cb + r) * 8);
#pragma unroll
    for (int er = 0; er < 4; ++er) {
      const s16x8 af = *(const s16x8*)&X[(er * 16 + r) * SXE + kk * 32 + 8 * g];
      acc[er] = __builtin_amdgcn_mfma_f32_16x16x32_bf16(af, bf, acc[er], 0, 0, 0);
    }
  }

  // ---- relu -> X2 ----
#pragma unroll
  for (int er = 0; er < 4; ++er)
#pragma unroll
    for (int i = 0; i < 4; ++i)
      X2[(er * 16 + 4 * g + i) * SX2 + cb + r] = f2bf(fmaxf(acc[er][i], 0.0f));
  __syncthreads();

  // ---- layer 2: K=64 ----
  const float bias2 = b2[cb + r];
  f32x4 a2[4];
  a2[0] = a2[1] = a2[2] = a2[3] = (f32x4){bias2, bias2, bias2, bias2};
#pragma unroll
  for (int kk = 0; kk < 2; ++kk) {
    const s16x8 bf = *(const s16x8*)(w2p + (size_t)((kk * 4 + g) * 64 + cb + r) * 8);
#pragma unroll
    for (int er = 0; er < 4; ++er) {
      const s16x8 af = *(const s16x8*)&X2[(er * 16 + r) * SX2 + kk * 32 + 8 * g];
      a2[er] = __builtin_amdgcn_mfma_f32_16x16x32_bf16(af, bf, a2[er], 0, 0, 0);
    }
  }
  __syncthreads();   // all layer-2 reads of X2 done -> reuse X2 as message tile

  // ---- write messages (bf16) into X2 ----
#pragma unroll
  for (int er = 0; er < 4; ++er)
#pragma unroll
    for (int i = 0; i < 4; ++i)
      X2[(er * 16 + 4 * g + i) * SX2 + cb + r] = f2bf(a2[er][i]);
  __syncthreads();

  // ---- segmented reduce: wave w sums rows [16w,16w+16), lane = channel ----
  // tgts[] is non-decreasing (CSR order); flush one f32 atomic per run piece.
  {
    float sum = 0.0f;
    int cur = -1;
#pragma unroll 4
    for (int i = 0; i < 16; ++i) {
      const int row = 16 * w + i;
      const int t = tgts[row];                       // wave-uniform
      const float v = bf2f(X2[row * SX2 + lane]);    // 128B coalesced row
      if (t != cur) {
        if (cur >= 0) atomicAdd(agg + (size_t)cur * 64 + lane, sum);
        cur = t;
        sum = 0.0f;
      }
      if (t >= 0) sum += v;
    }
    if (cur >= 0) atomicAdd(agg + (size_t)cur * 64 + lane, sum);
  }
}

// ---------------- node MLP (MFMA) ----------------
__global__ __launch_bounds__(256, 4)
void node_mlp_mfma(const unsigned short* __restrict__ hb, const float* __restrict__ agg,
                   const unsigned short* __restrict__ w1p, const float* __restrict__ b1,
                   const unsigned short* __restrict__ w2p, const float* __restrict__ b2,
                   float* __restrict__ out, int N) {
  __shared__ unsigned short X[64 * SXN];
  __shared__ unsigned short X2[64 * SX2];

  const int tid = threadIdx.x;
  const int w = tid >> 6, lane = tid & 63;
  const int g = lane >> 4, r = lane & 15;
  const long long base = (long long)blockIdx.x * 64;

  {
    const int row = tid >> 2, q = tid & 3;
    long long n = base + row;
    if (n >= N) n = N - 1;
    const u16x8* hr = (const u16x8*)(hb + (size_t)n * 64);
    *(u16x8*)&X[row * SXN + 16 * q] = hr[2 * q];
    *(u16x8*)&X[row * SXN + 16 * q + 8] = hr[2 * q + 1];
    const float4* ar = (const float4*)(agg + (size_t)n * 64);
    *(u16x8*)&X[row * SXN + 64 + 16 * q] = pack8(ar[4 * q], ar[4 * q + 1]);
    *(u16x8*)&X[row * SXN + 64 + 16 * q + 8] = pack8(ar[4 * q + 2], ar[4 * q + 3]);
  }
  __syncthreads();

  const int cb = w * 16;

  const float bias1 = b1[cb + r];
  f32x4 acc[4];
  acc[0] = acc[1] = acc[2] = acc[3] = (f32x4){bias1, bias1, bias1, bias1};
#pragma unroll
  for (int kk = 0; kk < 4; ++kk) {
    const s16x8 bf = *(const s16x8*)(w1p + (size_t)((kk * 4 + g) * 64 + cb + r) * 8);
#pragma unroll
    for (int er = 0; er < 4; ++er) {
      const s16x8 af = *(const s16x8*)&X[(er * 16 + r) * SXN + kk * 32 + 8 * g];
      acc[er] = __builtin_amdgcn_mfma_f32_16x16x32_bf16(af, bf, acc[er], 0, 0, 0);
    }
  }

#pragma unroll
  for (int er = 0; er < 4; ++er)
#pragma unroll
    for (int i = 0; i < 4; ++i)
      X2[(er * 16 + 4 * g + i) * SX2 + cb + r] = f2bf(fmaxf(acc[er][i], 0.0f));
  __syncthreads();

  const float bias2 = b2[cb + r];
  f32x4 a2[4];
  a2[0] = a2[1] = a2[2] = a2[3] = (f32x4){bias2, bias2, bias2, bias2};
#pragma unroll
  for (int kk = 0; kk < 2; ++kk) {
    const s16x8 bf = *(const s16x8*)(w2p + (size_t)((kk * 4 + g) * 64 + cb + r) * 8);
#pragma unroll
    for (int er = 0; er < 4; ++er) {
      const s16x8 af = *(const s16x8*)&X2[(er * 16 + r) * SX2 + kk * 32 + 8 * g];
      a2[er] = __builtin_amdgcn_mfma_f32_16x16x32_bf16(af, bf, a2[er], 0, 0, 0);
    }
  }

#pragma unroll
  for (int er = 0; er < 4; ++er)
#pragma unroll
    for (int i = 0; i < 4; ++i) {
      const long long n = base + er * 16 + 4 * g + i;
      if (n < N) out[n * 64 + cb + r] = a2[er][i];
    }
}

// ---------------- host ----------------
extern "C" void kernel_launch(void* const* d_in, const int* in_sizes, int n_in,
                              void* d_out, int out_size, void* d_ws, size_t ws_size,
                              hipStream_t stream) {
  const float* h   = (const float*)d_in[0];
  const int*   ei  = (const int*)d_in[1];
  const float* ef  = (const float*)d_in[2];
  const float* eW1 = (const float*)d_in[3];
  const float* eb1 = (const float*)d_in[4];
  const float* eW2 = (const float*)d_in[5];
  const float* eb2 = (const float*)d_in[6];
  const float* uW1 = (const float*)d_in[7];
  const float* ub1 = (const float*)d_in[8];
  const float* uW2 = (const float*)d_in[9];
  const float* ub2 = (const float*)d_in[10];
  float* out = (float*)d_out;

  const int N = in_sizes[0] / 64;   // 100000
  const int E = in_sizes[1] / 2;    // 1600000
  const int nchunks = (N + SCAN_CHUNK - 1) / SCAN_CHUNK;

  size_t off = 0;
  auto alloc = [&](size_t bytes) { size_t o = off; off += (bytes + 255) & ~(size_t)255; return o; };
  const size_t agg_off    = alloc((size_t)N * 64 * 4);   // 25.6 MB f32 (atomic target)
  const size_t deg_off    = alloc((size_t)N * 4);        // adjacent to agg: single memset
  const size_t hb_off     = alloc((size_t)N * 64 * 2);   // 12.8 MB bf16
  const size_t w1p_off    = alloc((size_t)160 * 64 * 2);
  const size_t w2p_off    = alloc((size_t)64 * 64 * 2);
  const size_t uw1p_off   = alloc((size_t)128 * 64 * 2);
  const size_t uw2p_off   = alloc((size_t)64 * 64 * 2);
  const size_t esrc_off   = alloc((size_t)E * 4);
  const size_t etgt_off   = alloc((size_t)E * 4);
  const size_t eeid_off   = alloc((size_t)E * 4);
  const size_t start_off  = alloc((size_t)N * 4);
  const size_t cursor_off = alloc((size_t)N * 4);
  const size_t csum_off   = alloc((size_t)nchunks * 4);
  const size_t coff_off   = alloc((size_t)nchunks * 4);
  char* ws = (char*)d_ws;

  float*          agg  = (float*)(ws + agg_off);
  int*            deg  = (int*)(ws + deg_off);
  unsigned short* hb   = (unsigned short*)(ws + hb_off);
  unsigned short* w1p  = (unsigned short*)(ws + w1p_off);
  unsigned short* w2p  = (unsigned short*)(ws + w2p_off);
  unsigned short* uw1p = (unsigned short*)(ws + uw1p_off);
  unsigned short* uw2p = (unsigned short*)(ws + uw2p_off);
  int* esrc   = (int*)(ws + esrc_off);
  int* etgt   = (int*)(ws + etgt_off);
  int* eeid   = (int*)(ws + eeid_off);
  int* start  = (int*)(ws + start_off);
  int* cursor = (int*)(ws + cursor_off);
  int* csum   = (int*)(ws + csum_off);
  int* coff   = (int*)(ws + coff_off);

  // zero agg + deg in one memset (adjacent)
  hipMemsetAsync(ws + agg_off, 0, deg_off + (size_t)N * 4 - agg_off, stream);

  // pre-pass
  const long long htot = (long long)N * 64;
  conv_bf16<<<(int)((htot / 4 + 255) / 256), 256, 0, stream>>>(h, hb, htot);
  pack_weights_all<<<(52 * 64 + 255) / 256, 256, 0, stream>>>(eW1, eW2, uW1, uW2, w1p, w2p, uw1p, uw2p);

  // CSR build
  hist_deg<<<1024, 256, 0, stream>>>(ei, deg, E);
  scan_chunks<<<nchunks, 256, 0, stream>>>(deg, start, csum, N);
  scan_sums<<<1, 256, 0, stream>>>(csum, coff, nchunks);
  add_offsets<<<(N + 255) / 256, 256, 0, stream>>>(start, coff, cursor, N);
  fill_elist<<<1024, 256, 0, stream>>>(ei, cursor, esrc, etgt, eeid, E);

  // fused pipeline
  edge_mlp_fused<<<(E + 63) / 64, 256, 0, stream>>>(hb, ef, w1p, eb1, w2p, eb2,
                                                    esrc, etgt, eeid, agg, E);
  node_mlp_mfma<<<(N + 63) / 64, 256, 0, stream>>>(hb, agg, uw1p, ub1, uw2p, ub2, out, N);
}

// Round 6
// 326.317 us; speedup vs baseline: 9.3333x; 1.1036x over previous
//
#include <hip/hip_runtime.h>

// MessagePassingLayer, Round 6: persistent pipelined edge kernel + AoS fill.
// R5 post-mortem: edge kernel latency-bound (MfmaUtil 12%, HBM 20%) on the
// per-tile staging chain; ~200us outside the edge kernel (fill_elist 3-plane
// scatter = 192B lines/edge). Changes:
//  (1) edge kernel: 768 persistent blocks x ~33 tiles, 2-level register
//      prefetch (aoe for t+2, h/ef gathers for t+1), double-buffered X LDS.
//      W-fragments + biases hoisted to registers BEFORE the loop so no inner
//      global load forces a vmcnt drain of the in-flight gathers.
//  (2) fill_elist writes one int4 {s,t,e,0} per edge (1 cache line vs 3).

typedef __attribute__((ext_vector_type(8))) short s16x8;     // MFMA A/B frag
typedef __attribute__((ext_vector_type(4))) float f32x4;     // MFMA C/D frag
typedef __attribute__((ext_vector_type(8))) unsigned short u16x8;

#define SCAN_CHUNK 1024
#define SXE 168   // edge X tile row stride (bf16)
#define SXN 136   // node X tile row stride
#define SX2 72    // activation/message tile stride
#define NBLK_EDGE 768

__device__ __forceinline__ unsigned short f2bf(float f) {   // RNE f32->bf16
  unsigned int u = __builtin_bit_cast(unsigned int, f);
  u += 0x7fffu + ((u >> 16) & 1u);
  return (unsigned short)(u >> 16);
}
__device__ __forceinline__ float bf2f(unsigned short s) {
  unsigned int u = ((unsigned int)s) << 16;
  return __builtin_bit_cast(float, u);
}
__device__ __forceinline__ u16x8 pack8(const float4 a, const float4 b) {
  u16x8 r;
  r[0] = f2bf(a.x); r[1] = f2bf(a.y); r[2] = f2bf(a.z); r[3] = f2bf(a.w);
  r[4] = f2bf(b.x); r[5] = f2bf(b.y); r[6] = f2bf(b.z); r[7] = f2bf(b.w);
  return r;
}

// ---------------- pre-pass ----------------
__global__ void conv_bf16(const float* __restrict__ src, unsigned short* __restrict__ dst,
                          long long total) {
  const long long i = ((long long)blockIdx.x * blockDim.x + threadIdx.x) * 4;
  if (i + 3 < total) {
    const float4 v = *(const float4*)(src + i);
    ushort4 o;
    o.x = f2bf(v.x); o.y = f2bf(v.y); o.z = f2bf(v.z); o.w = f2bf(v.w);
    *(ushort4*)(dst + i) = o;
  } else {
    for (long long j = i; j < total; ++j) dst[j] = f2bf(src[j]);
  }
}

// Pack all 4 weight matrices into fragment order in one launch.
__global__ void pack_weights_all(const float* __restrict__ eW1, const float* __restrict__ eW2,
                                 const float* __restrict__ uW1, const float* __restrict__ uW2,
                                 unsigned short* __restrict__ w1p, unsigned short* __restrict__ w2p,
                                 unsigned short* __restrict__ uw1p, unsigned short* __restrict__ uw2p) {
  const int tid = blockIdx.x * blockDim.x + threadIdx.x;
  if (tid >= 52 * 64) return;
  const int c = tid & 63;
  int kg = tid >> 6;
  const float* src;
  unsigned short* dst;
  if (kg < 20)      { src = eW1; dst = w1p; }
  else if (kg < 28) { src = eW2; dst = w2p; kg -= 20; }
  else if (kg < 44) { src = uW1; dst = uw1p; kg -= 28; }
  else              { src = uW2; dst = uw2p; kg -= 44; }
#pragma unroll
  for (int e = 0; e < 8; ++e)
    dst[(size_t)(kg * 64 + c) * 8 + e] = f2bf(src[(size_t)(kg * 8 + e) * 64 + c]);
}

// ---------------- CSR build ----------------
__global__ void hist_deg(const int* __restrict__ ei, int* __restrict__ deg, int E) {
  for (long long e = (long long)blockIdx.x * blockDim.x + threadIdx.x; e < E;
       e += (long long)gridDim.x * blockDim.x)
    atomicAdd(&deg[ei[E + e]], 1);
}

__global__ void scan_chunks(const int* __restrict__ deg, int* __restrict__ start,
                            int* __restrict__ chunk_sums, int N) {
  __shared__ int sdata[256];
  const int tid = threadIdx.x;
  const int base = blockIdx.x * SCAN_CHUNK + tid * 4;
  int v[4];
  int sum = 0;
#pragma unroll
  for (int k = 0; k < 4; ++k) {
    v[k] = (base + k < N) ? deg[base + k] : 0;
    sum += v[k];
  }
  sdata[tid] = sum;
  __syncthreads();
  for (int off = 1; off < 256; off <<= 1) {
    int t = (tid >= off) ? sdata[tid - off] : 0;
    __syncthreads();
    sdata[tid] += t;
    __syncthreads();
  }
  int run = (tid == 0) ? 0 : sdata[tid - 1];
#pragma unroll
  for (int k = 0; k < 4; ++k) {
    if (base + k < N) start[base + k] = run;
    run += v[k];
  }
  if (tid == 255) chunk_sums[blockIdx.x] = sdata[255];
}

__global__ void scan_sums(const int* __restrict__ chunk_sums, int* __restrict__ chunk_offs,
                          int nchunks) {
  __shared__ int s[1024];
  const int tid = threadIdx.x;
  for (int i = tid; i < nchunks; i += blockDim.x) s[i] = chunk_sums[i];
  __syncthreads();
  if (tid == 0) {
    int run = 0;
    for (int i = 0; i < nchunks; ++i) { int v = s[i]; s[i] = run; run += v; }
  }
  __syncthreads();
  for (int i = tid; i < nchunks; i += blockDim.x) chunk_offs[i] = s[i];
}

__global__ void add_offsets(int* __restrict__ start, const int* __restrict__ chunk_offs,
                            int* __restrict__ cursor, int N) {
  const int i = blockIdx.x * blockDim.x + threadIdx.x;
  if (i < N) {
    const int sgl = start[i] + chunk_offs[i / SCAN_CHUNK];
    start[i] = sgl;
    cursor[i] = sgl;
  }
}

// AoS fill: one 16B write per edge
__global__ void fill_elist(const int* __restrict__ ei, int* __restrict__ cursor,
                           int4* __restrict__ aoe, int E) {
  for (long long e = (long long)blockIdx.x * blockDim.x + threadIdx.x; e < E;
       e += (long long)gridDim.x * blockDim.x) {
    const int t = ei[E + e];
    const int s = ei[e];
    const int pos = atomicAdd(&cursor[t], 1);
    aoe[pos] = make_int4(s, t, (int)e, 0);
  }
}

// ---------------- fused edge MLP: persistent, pipelined ----------------
// Fragment maps (mfma_f32_16x16x32_bf16, lane l: g=l>>4, r=l&15):
//   A[m][k]: m=r, k=8g+e   B[k][n]: n=r, k=8g+e   D[m][n]: n=r, m=4g+i
__global__ __launch_bounds__(256, 3)
void edge_mlp_fused(const unsigned short* __restrict__ hb, const float* __restrict__ ef,
                    const unsigned short* __restrict__ w1p, const float* __restrict__ b1,
                    const unsigned short* __restrict__ w2p, const float* __restrict__ b2,
                    const int4* __restrict__ aoe, float* __restrict__ agg,
                    int E, int ntiles, int tpb) {
  __shared__ unsigned short X[2][64 * SXE];   // 43 KB: double-buffered input tile
  __shared__ unsigned short X2[64 * SX2];     // 9.2 KB: relu acts, then message tile
  __shared__ int tgts[2][64];

  const int tid = threadIdx.x;
  const int w = tid >> 6, lane = tid & 63;
  const int g = lane >> 4, r = lane & 15;
  const int row = tid >> 2, q = tid & 3;

  const int t0 = blockIdx.x * tpb;
  const int t1 = min(t0 + tpb, ntiles);
  if (t0 >= t1) return;

  const long long Emax = (long long)E - 1;
  const int cb = w * 16;

  // ---- hoist W fragments + biases into registers (loop-invariant) ----
  // Inner loop then has NO global loads except the prefetch gathers, so no
  // compiler waitcnt can force a drain of in-flight gathers.
  s16x8 bfrag1[5], bfrag2[2];
#pragma unroll
  for (int kk = 0; kk < 5; ++kk)
    bfrag1[kk] = *(const s16x8*)(w1p + (size_t)((kk * 4 + g) * 64 + cb + r) * 8);
#pragma unroll
  for (int kk = 0; kk < 2; ++kk)
    bfrag2[kk] = *(const s16x8*)(w2p + (size_t)((kk * 4 + g) * 64 + cb + r) * 8);
  const float bias1 = b1[cb + r];
  const float bias2 = b2[cb + r];

  // ---- staging registers ----
  int4 nxt_aoe;          // aoe for tile t+1 (becomes gather source)
  u16x8 hs0, hs1, ht0, ht1;
  float4 fea, feb;

  auto load_aoe = [&](int t) -> int4 {
    long long p = (long long)t * 64 + row;
    if (p > Emax) p = Emax;
    return aoe[p];
  };
  auto issue_gathers = [&](const int4 a) {
    const u16x8* hs = (const u16x8*)(hb + (size_t)a.x * 64);
    const u16x8* ht = (const u16x8*)(hb + (size_t)a.y * 64);
    hs0 = hs[2 * q]; hs1 = hs[2 * q + 1];
    ht0 = ht[2 * q]; ht1 = ht[2 * q + 1];
    const float4* fp = (const float4*)(ef + (size_t)a.z * 32);
    fea = fp[2 * q]; feb = fp[2 * q + 1];   // raw f32; converted at write time
  };
  auto write_tile = [&](int buf, int t, const int4 a) {
    unsigned short* Xb = &X[buf][0];
    *(u16x8*)&Xb[row * SXE + 16 * q] = hs0;
    *(u16x8*)&Xb[row * SXE + 16 * q + 8] = hs1;
    *(u16x8*)&Xb[row * SXE + 64 + 16 * q] = ht0;
    *(u16x8*)&Xb[row * SXE + 64 + 16 * q + 8] = ht1;
    *(u16x8*)&Xb[row * SXE + 128 + 8 * q] = pack8(fea, feb);
    if (q == 0) tgts[buf][row] = ((long long)t * 64 + row <= Emax && (long long)t * 64 + row < E)
                                     ? a.y : -1;
  };

  // ---- prologue: stage tile t0, start aoe for t0+1 ----
  {
    const int4 a0 = load_aoe(t0);
    nxt_aoe = load_aoe(t0 + 1 < t1 ? t0 + 1 : t0);
    issue_gathers(a0);
    write_tile(0, t0, a0);
  }
  __syncthreads();

  for (int t = t0; t < t1; ++t) {
    const int cur = (t - t0) & 1;
    const bool have_next = (t + 1 < t1);

    // ---- issue prefetch for t+1; refill aoe for t+2 ----
    int4 ga = nxt_aoe;
    if (have_next) {
      nxt_aoe = load_aoe(t + 2 < t1 ? t + 2 : t + 1);
      issue_gathers(ga);   // in flight across the whole compute phase
    }

    // ---- layer 1: K=160 on X[cur] ----
    f32x4 acc[4];
    acc[0] = acc[1] = acc[2] = acc[3] = (f32x4){bias1, bias1, bias1, bias1};
#pragma unroll
    for (int kk = 0; kk < 5; ++kk) {
#pragma unroll
      for (int er = 0; er < 4; ++er) {
        const s16x8 af = *(const s16x8*)&X[cur][(er * 16 + r) * SXE + kk * 32 + 8 * g];
        acc[er] = __builtin_amdgcn_mfma_f32_16x16x32_bf16(af, bfrag1[kk], acc[er], 0, 0, 0);
      }
    }

    // ---- relu -> X2 ----
#pragma unroll
    for (int er = 0; er < 4; ++er)
#pragma unroll
      for (int i = 0; i < 4; ++i)
        X2[(er * 16 + 4 * g + i) * SX2 + cb + r] = f2bf(fmaxf(acc[er][i], 0.0f));
    __syncthreads();

    // ---- layer 2: K=64 ----
    f32x4 a2[4];
    a2[0] = a2[1] = a2[2] = a2[3] = (f32x4){bias2, bias2, bias2, bias2};
#pragma unroll
    for (int kk = 0; kk < 2; ++kk) {
#pragma unroll
      for (int er = 0; er < 4; ++er) {
        const s16x8 af = *(const s16x8*)&X2[(er * 16 + r) * SX2 + kk * 32 + 8 * g];
        a2[er] = __builtin_amdgcn_mfma_f32_16x16x32_bf16(af, bfrag2[kk], a2[er], 0, 0, 0);
      }
    }
    __syncthreads();   // all layer-2 reads done -> X2 becomes message tile

    // ---- messages (bf16) into X2 ----
#pragma unroll
    for (int er = 0; er < 4; ++er)
#pragma unroll
      for (int i = 0; i < 4; ++i)
        X2[(er * 16 + 4 * g + i) * SX2 + cb + r] = f2bf(a2[er][i]);
    __syncthreads();

    // ---- write next tile's X buffer (vmcnt wait for gathers lands HERE) ----
    if (have_next) write_tile(cur ^ 1, t + 1, ga);

    // ---- segmented reduce: wave w sums rows [16w,16w+16), lane = channel ----
    {
      float sum = 0.0f;
      int curt = -1;
#pragma unroll 4
      for (int i = 0; i < 16; ++i) {
        const int rr = 16 * w + i;
        const int tt = tgts[cur][rr];                   // wave-uniform
        const float v = bf2f(X2[rr * SX2 + lane]);
        if (tt != curt) {
          if (curt >= 0) atomicAdd(agg + (size_t)curt * 64 + lane, sum);
          curt = tt;
          sum = 0.0f;
        }
        if (tt >= 0) sum += v;
      }
      if (curt >= 0) atomicAdd(agg + (size_t)curt * 64 + lane, sum);
    }
    __syncthreads();   // X2 free + X[cur^1] staged for next iter
  }
}

// ---------------- node MLP (MFMA) ----------------
__global__ __launch_bounds__(256, 4)
void node_mlp_mfma(const unsigned short* __restrict__ hb, const float* __restrict__ agg,
                   const unsigned short* __restrict__ w1p, const float* __restrict__ b1,
                   const unsigned short* __restrict__ w2p, const float* __restrict__ b2,
                   float* __restrict__ out, int N) {
  __shared__ unsigned short X[64 * SXN];
  __shared__ unsigned short X2[64 * SX2];

  const int tid = threadIdx.x;
  const int w = tid >> 6, lane = tid & 63;
  const int g = lane >> 4, r = lane & 15;
  const long long base = (long long)blockIdx.x * 64;

  {
    const int row = tid >> 2, q = tid & 3;
    long long n = base + row;
    if (n >= N) n = N - 1;
    const u16x8* hr = (const u16x8*)(hb + (size_t)n * 64);
    *(u16x8*)&X[row * SXN + 16 * q] = hr[2 * q];
    *(u16x8*)&X[row * SXN + 16 * q + 8] = hr[2 * q + 1];
    const float4* ar = (const float4*)(agg + (size_t)n * 64);
    *(u16x8*)&X[row * SXN + 64 + 16 * q] = pack8(ar[4 * q], ar[4 * q + 1]);
    *(u16x8*)&X[row * SXN + 64 + 16 * q + 8] = pack8(ar[4 * q + 2], ar[4 * q + 3]);
  }
  __syncthreads();

  const int cb = w * 16;

  const float bias1 = b1[cb + r];
  f32x4 acc[4];
  acc[0] = acc[1] = acc[2] = acc[3] = (f32x4){bias1, bias1, bias1, bias1};
#pragma unroll
  for (int kk = 0; kk < 4; ++kk) {
    const s16x8 bf = *(const s16x8*)(w1p + (size_t)((kk * 4 + g) * 64 + cb + r) * 8);
#pragma unroll
    for (int er = 0; er < 4; ++er) {
      const s16x8 af = *(const s16x8*)&X[(er * 16 + r) * SXN + kk * 32 + 8 * g];
      acc[er] = __builtin_amdgcn_mfma_f32_16x16x32_bf16(af, bf, acc[er], 0, 0, 0);
    }
  }

#pragma unroll
  for (int er = 0; er < 4; ++er)
#pragma unroll
    for (int i = 0; i < 4; ++i)
      X2[(er * 16 + 4 * g + i) * SX2 + cb + r] = f2bf(fmaxf(acc[er][i], 0.0f));
  __syncthreads();

  const float bias2 = b2[cb + r];
  f32x4 a2[4];
  a2[0] = a2[1] = a2[2] = a2[3] = (f32x4){bias2, bias2, bias2, bias2};
#pragma unroll
  for (int kk = 0; kk < 2; ++kk) {
    const s16x8 bf = *(const s16x8*)(w2p + (size_t)((kk * 4 + g) * 64 + cb + r) * 8);
#pragma unroll
    for (int er = 0; er < 4; ++er) {
      const s16x8 af = *(const s16x8*)&X2[(er * 16 + r) * SX2 + kk * 32 + 8 * g];
      a2[er] = __builtin_amdgcn_mfma_f32_16x16x32_bf16(af, bf, a2[er], 0, 0, 0);
    }
  }

#pragma unroll
  for (int er = 0; er < 4; ++er)
#pragma unroll
    for (int i = 0; i < 4; ++i) {
      const long long n = base + er * 16 + 4 * g + i;
      if (n < N) out[n * 64 + cb + r] = a2[er][i];
    }
}

// ---------------- host ----------------
extern "C" void kernel_launch(void* const* d_in, const int* in_sizes, int n_in,
                              void* d_out, int out_size, void* d_ws, size_t ws_size,
                              hipStream_t stream) {
  const float* h   = (const float*)d_in[0];
  const int*   ei  = (const int*)d_in[1];
  const float* ef  = (const float*)d_in[2];
  const float* eW1 = (const float*)d_in[3];
  const float* eb1 = (const float*)d_in[4];
  const float* eW2 = (const float*)d_in[5];
  const float* eb2 = (const float*)d_in[6];
  const float* uW1 = (const float*)d_in[7];
  const float* ub1 = (const float*)d_in[8];
  const float* uW2 = (const float*)d_in[9];
  const float* ub2 = (const float*)d_in[10];
  float* out = (float*)d_out;

  const int N = in_sizes[0] / 64;   // 100000
  const int E = in_sizes[1] / 2;    // 1600000
  const int nchunks = (N + SCAN_CHUNK - 1) / SCAN_CHUNK;
  const int ntiles = (E + 63) / 64;
  const int nblk = ntiles < NBLK_EDGE ? ntiles : NBLK_EDGE;
  const int tpb = (ntiles + nblk - 1) / nblk;

  size_t off = 0;
  auto alloc = [&](size_t bytes) { size_t o = off; off += (bytes + 255) & ~(size_t)255; return o; };
  const size_t agg_off    = alloc((size_t)N * 64 * 4);   // 25.6 MB (atomic target)
  const size_t deg_off    = alloc((size_t)N * 4);        // adjacent: single memset
  const size_t hb_off     = alloc((size_t)N * 64 * 2);
  const size_t w1p_off    = alloc((size_t)160 * 64 * 2);
  const size_t w2p_off    = alloc((size_t)64 * 64 * 2);
  const size_t uw1p_off   = alloc((size_t)128 * 64 * 2);
  const size_t uw2p_off   = alloc((size_t)64 * 64 * 2);
  const size_t aoe_off    = alloc((size_t)E * 16);       // 25.6 MB AoS {s,t,e,0}
  const size_t start_off  = alloc((size_t)N * 4);
  const size_t cursor_off = alloc((size_t)N * 4);
  const size_t csum_off   = alloc((size_t)nchunks * 4);
  const size_t coff_off   = alloc((size_t)nchunks * 4);
  char* ws = (char*)d_ws;

  float*          agg  = (float*)(ws + agg_off);
  int*            deg  = (int*)(ws + deg_off);
  unsigned short* hb   = (unsigned short*)(ws + hb_off);
  unsigned short* w1p  = (unsigned short*)(ws + w1p_off);
  unsigned short* w2p  = (unsigned short*)(ws + w2p_off);
  unsigned short* uw1p = (unsigned short*)(ws + uw1p_off);
  unsigned short* uw2p = (unsigned short*)(ws + uw2p_off);
  int4* aoe   = (int4*)(ws + aoe_off);
  int* start  = (int*)(ws + start_off);
  int* cursor = (int*)(ws + cursor_off);
  int* csum   = (int*)(ws + csum_off);
  int* coff   = (int*)(ws + coff_off);

  hipMemsetAsync(ws + agg_off, 0, deg_off + (size_t)N * 4 - agg_off, stream);

  const long long htot = (long long)N * 64;
  conv_bf16<<<(int)((htot / 4 + 255) / 256), 256, 0, stream>>>(h, hb, htot);
  pack_weights_all<<<(52 * 64 + 255) / 256, 256, 0, stream>>>(eW1, eW2, uW1, uW2, w1p, w2p, uw1p, uw2p);

  hist_deg<<<1024, 256, 0, stream>>>(ei, deg, E);
  scan_chunks<<<nchunks, 256, 0, stream>>>(deg, start, csum, N);
  scan_sums<<<1, 256, 0, stream>>>(csum, coff, nchunks);
  add_offsets<<<(N + 255) / 256, 256, 0, stream>>>(start, coff, cursor, N);
  fill_elist<<<1024, 256, 0, stream>>>(ei, cursor, aoe, E);

  edge_mlp_fused<<<nblk, 256, 0, stream>>>(hb, ef, w1p, eb1, w2p, eb2, aoe, agg, E, ntiles, tpb);
  node_mlp_mfma<<<(N + 63) / 64, 256, 0, stream>>>(hb, agg, uw1p, ub1, uw2p, ub2, out, N);
}

// Round 7
// 303.177 us; speedup vs baseline: 10.0456x; 1.0763x over previous
//
#include <hip/hip_runtime.h>

// MessagePassingLayer, Round 7: lgkm-only barriers + band-local L2/reduce.
// R6 post-mortem: __syncthreads() emits s_waitcnt vmcnt(0) -> every barrier
// drained the prefetch gathers + atomics (5x/tile); LDS double-buffer cost
// occupancy 53->30%. Fixes:
//  (1) raw s_barrier with lgkmcnt(0) only -- vmcnt waits happen only at
//      data-dependence (write_tile), atomics never waited.
//  (2) layer-2 is edge-band-local: wave w computes ALL 64 out-channels for
//      its 16 edges (W2 fragments from an 8KB LDS copy); msg tile rows
//      16w..16w+15 written entirely by wave w -> reduce needs NO barrier.
//      Barriers/tile: 5 -> 2.
//  (3) single X buffer (X dead after layer-1 barrier) -> 39.5KB LDS, 4 blk/CU.
//  (4) conv+pack+hist fused into one prep kernel.

typedef __attribute__((ext_vector_type(8))) short s16x8;     // MFMA A/B frag
typedef __attribute__((ext_vector_type(4))) float f32x4;     // MFMA C/D frag
typedef __attribute__((ext_vector_type(8))) unsigned short u16x8;

#define SCAN_CHUNK 1024
#define SXE 168   // edge X tile row stride (bf16)
#define SXN 136   // node X tile row stride
#define SX2 72    // activation/message tile stride
#define NBLK_EDGE 1024

__device__ __forceinline__ unsigned short f2bf(float f) {   // RNE f32->bf16
  unsigned int u = __builtin_bit_cast(unsigned int, f);
  u += 0x7fffu + ((u >> 16) & 1u);
  return (unsigned short)(u >> 16);
}
__device__ __forceinline__ float bf2f(unsigned short s) {
  unsigned int u = ((unsigned int)s) << 16;
  return __builtin_bit_cast(float, u);
}
__device__ __forceinline__ u16x8 pack8(const float4 a, const float4 b) {
  u16x8 r;
  r[0] = f2bf(a.x); r[1] = f2bf(a.y); r[2] = f2bf(a.z); r[3] = f2bf(a.w);
  r[4] = f2bf(b.x); r[5] = f2bf(b.y); r[6] = f2bf(b.z); r[7] = f2bf(b.w);
  return r;
}

// workgroup barrier that waits LDS ops only -- does NOT drain vmcnt
// (prefetch gathers / atomics stay in flight across it).
__device__ __forceinline__ void bar_lgkm() {
  __builtin_amdgcn_sched_barrier(0);
  asm volatile("s_waitcnt lgkmcnt(0)" ::: "memory");
  __builtin_amdgcn_s_barrier();
  __builtin_amdgcn_sched_barrier(0);
}

// ---------------- fused pre-pass: conv_bf16 + pack_weights + hist_deg ----------------
__global__ void prep(const float* __restrict__ h, unsigned short* __restrict__ hb, long long htot,
                     const float* __restrict__ eW1, const float* __restrict__ eW2,
                     const float* __restrict__ uW1, const float* __restrict__ uW2,
                     unsigned short* __restrict__ w1p, unsigned short* __restrict__ w2p,
                     unsigned short* __restrict__ uw1p, unsigned short* __restrict__ uw2p,
                     const int* __restrict__ ei, int* __restrict__ deg, int E,
                     int conv_blocks) {
  const int b = blockIdx.x;
  const int tid = threadIdx.x;
  if (b < conv_blocks) {
    const long long i = ((long long)b * 256 + tid) * 4;
    if (i + 3 < htot) {
      const float4 v = *(const float4*)(h + i);
      ushort4 o;
      o.x = f2bf(v.x); o.y = f2bf(v.y); o.z = f2bf(v.z); o.w = f2bf(v.w);
      *(ushort4*)(hb + i) = o;
    } else {
      for (long long j = i; j < htot; ++j) hb[j] = f2bf(h[j]);
    }
  } else if (b < conv_blocks + 13) {
    const int t2 = (b - conv_blocks) * 256 + tid;
    if (t2 < 52 * 64) {
      const int c = t2 & 63;
      int kg = t2 >> 6;
      const float* src;
      unsigned short* dst;
      if (kg < 20)      { src = eW1; dst = w1p; }
      else if (kg < 28) { src = eW2; dst = w2p; kg -= 20; }
      else if (kg < 44) { src = uW1; dst = uw1p; kg -= 28; }
      else              { src = uW2; dst = uw2p; kg -= 44; }
#pragma unroll
      for (int e = 0; e < 8; ++e)
        dst[(size_t)(kg * 64 + c) * 8 + e] = f2bf(src[(size_t)(kg * 8 + e) * 64 + c]);
    }
  } else {
    const int hbk = b - conv_blocks - 13;   // 1024 hist blocks
    for (long long e = (long long)hbk * 256 + tid; e < E; e += 1024LL * 256)
      atomicAdd(&deg[ei[E + e]], 1);
  }
}

// ---------------- CSR build ----------------
__global__ void scan_chunks(const int* __restrict__ deg, int* __restrict__ start,
                            int* __restrict__ chunk_sums, int N) {
  __shared__ int sdata[256];
  const int tid = threadIdx.x;
  const int base = blockIdx.x * SCAN_CHUNK + tid * 4;
  int v[4];
  int sum = 0;
#pragma unroll
  for (int k = 0; k < 4; ++k) {
    v[k] = (base + k < N) ? deg[base + k] : 0;
    sum += v[k];
  }
  sdata[tid] = sum;
  __syncthreads();
  for (int off = 1; off < 256; off <<= 1) {
    int t = (tid >= off) ? sdata[tid - off] : 0;
    __syncthreads();
    sdata[tid] += t;
    __syncthreads();
  }
  int run = (tid == 0) ? 0 : sdata[tid - 1];
#pragma unroll
  for (int k = 0; k < 4; ++k) {
    if (base + k < N) start[base + k] = run;
    run += v[k];
  }
  if (tid == 255) chunk_sums[blockIdx.x] = sdata[255];
}

__global__ void scan_sums(const int* __restrict__ chunk_sums, int* __restrict__ chunk_offs,
                          int nchunks) {
  __shared__ int s[1024];
  const int tid = threadIdx.x;
  for (int i = tid; i < nchunks; i += blockDim.x) s[i] = chunk_sums[i];
  __syncthreads();
  if (tid == 0) {
    int run = 0;
    for (int i = 0; i < nchunks; ++i) { int v = s[i]; s[i] = run; run += v; }
  }
  __syncthreads();
  for (int i = tid; i < nchunks; i += blockDim.x) chunk_offs[i] = s[i];
}

__global__ void add_offsets(int* __restrict__ start, const int* __restrict__ chunk_offs,
                            int* __restrict__ cursor, int N) {
  const int i = blockIdx.x * blockDim.x + threadIdx.x;
  if (i < N) {
    const int sgl = start[i] + chunk_offs[i / SCAN_CHUNK];
    start[i] = sgl;
    cursor[i] = sgl;
  }
}

// AoS fill: one 16B write per edge
__global__ void fill_elist(const int* __restrict__ ei, int* __restrict__ cursor,
                           int4* __restrict__ aoe, int E) {
  for (long long e = (long long)blockIdx.x * blockDim.x + threadIdx.x; e < E;
       e += (long long)gridDim.x * blockDim.x) {
    const int t = ei[E + e];
    const int s = ei[e];
    const int pos = atomicAdd(&cursor[t], 1);
    aoe[pos] = make_int4(s, t, (int)e, 0);
  }
}

// ---------------- fused edge MLP: persistent, pipelined, 2 barriers/tile ----------------
// Fragment maps (mfma_f32_16x16x32_bf16, lane l: g=l>>4, r=l&15):
//   A[m][k]: m=r, k=8g+e   B[k][n]: n=r, k=8g+e   D[m][n]: n=r, m=4g+i
__global__ __launch_bounds__(256, 4)
void edge_mlp_fused(const unsigned short* __restrict__ hb, const float* __restrict__ ef,
                    const unsigned short* __restrict__ w1p, const float* __restrict__ b1,
                    const unsigned short* __restrict__ w2p, const float* __restrict__ b2,
                    const int4* __restrict__ aoe, float* __restrict__ agg,
                    int E, int ntiles, int tpb) {
  __shared__ unsigned short X[64 * SXE];    // 21.5 KB input tile (single buffer)
  __shared__ unsigned short X2[64 * SX2];   // 9.2 KB acts, then message tile
  __shared__ unsigned short W2L[64 * 64];   // 8 KB W2 fragments
  __shared__ int tgts[2][64];

  const int tid = threadIdx.x;
  const int w = tid >> 6, lane = tid & 63;
  const int g = lane >> 4, r = lane & 15;
  const int row = tid >> 2, q = tid & 3;

  // one-time: W2 fragment table -> LDS (covered by prologue barrier)
  {
    const int i = tid * 16;
    *(u16x8*)&W2L[i] = *(const u16x8*)&w2p[i];
    *(u16x8*)&W2L[i + 8] = *(const u16x8*)&w2p[i + 8];
  }

  const int t0 = blockIdx.x * tpb;
  const int t1 = min(t0 + tpb, ntiles);
  if (t0 >= t1) return;

  const long long Emax = (long long)E - 1;
  const int cb = w * 16;

  // hoisted loop invariants: W1 fragments + biases (no global loads in loop
  // body except the prefetch gathers -> no spurious vmcnt drains)
  s16x8 bfrag1[5];
#pragma unroll
  for (int kk = 0; kk < 5; ++kk)
    bfrag1[kk] = *(const s16x8*)(w1p + (size_t)((kk * 4 + g) * 64 + cb + r) * 8);
  const float bias1 = b1[cb + r];
  float b2v[4];
#pragma unroll
  for (int nb = 0; nb < 4; ++nb) b2v[nb] = b2[nb * 16 + r];

  // staging registers (tile t+1)
  int4 nxt_aoe;
  u16x8 hs0, hs1, ht0, ht1;
  float4 fea, feb;

  auto load_aoe = [&](int t) -> int4 {
    long long p = (long long)t * 64 + row;
    if (p > Emax) p = Emax;
    return aoe[p];
  };
  auto issue_gathers = [&](const int4 a) {
    const u16x8* hs = (const u16x8*)(hb + (size_t)a.x * 64);
    const u16x8* ht = (const u16x8*)(hb + (size_t)a.y * 64);
    hs0 = hs[2 * q]; hs1 = hs[2 * q + 1];
    ht0 = ht[2 * q]; ht1 = ht[2 * q + 1];
    const float4* fp = (const float4*)(ef + (size_t)a.z * 32);
    fea = fp[2 * q]; feb = fp[2 * q + 1];
  };
  auto write_tile = [&](int t, const int4 a) {
    *(u16x8*)&X[row * SXE + 16 * q] = hs0;
    *(u16x8*)&X[row * SXE + 16 * q + 8] = hs1;
    *(u16x8*)&X[row * SXE + 64 + 16 * q] = ht0;
    *(u16x8*)&X[row * SXE + 64 + 16 * q + 8] = ht1;
    *(u16x8*)&X[row * SXE + 128 + 8 * q] = pack8(fea, feb);
    if (q == 0) tgts[t & 1][row] = ((long long)t * 64 + row < E) ? a.y : -1;
  };

  // prologue: stage tile t0
  {
    const int4 a0 = load_aoe(t0);
    nxt_aoe = load_aoe(t0 + 1 < t1 ? t0 + 1 : t0);
    issue_gathers(a0);
    write_tile(t0, a0);
  }
  bar_lgkm();

  for (int t = t0; t < t1; ++t) {
    const bool have_next = (t + 1 < t1);

    // issue prefetch: aoe for t+2 (oldest), gathers for t+1 -- stay in
    // flight across L1 + barrier A (lgkm-only, no vmcnt drain)
    int4 ga = nxt_aoe;
    if (have_next) {
      nxt_aoe = load_aoe(t + 2 < t1 ? t + 2 : t + 1);
      issue_gathers(ga);
    }

    // ---- layer 1: wave w computes channels [cb,cb+16) for all 64 edges ----
    f32x4 acc[4];
    acc[0] = acc[1] = acc[2] = acc[3] = (f32x4){bias1, bias1, bias1, bias1};
#pragma unroll
    for (int kk = 0; kk < 5; ++kk) {
#pragma unroll
      for (int er = 0; er < 4; ++er) {
        const s16x8 af = *(const s16x8*)&X[(er * 16 + r) * SXE + kk * 32 + 8 * g];
        acc[er] = __builtin_amdgcn_mfma_f32_16x16x32_bf16(af, bfrag1[kk], acc[er], 0, 0, 0);
      }
    }

    bar_lgkm();   // A: X dead (all L1 reads done), prev reduce done -> X2 free

    // ---- relu -> X2 (cross-band); stage X for t+1 (X is dead) ----
#pragma unroll
    for (int er = 0; er < 4; ++er)
#pragma unroll
      for (int i = 0; i < 4; ++i)
        X2[(er * 16 + 4 * g + i) * SX2 + cb + r] = f2bf(fmaxf(acc[er][i], 0.0f));
    if (have_next) write_tile(t + 1, ga);   // vmcnt wait lands here only

    bar_lgkm();   // B: acts visible to all waves; X staged

    // ---- layer 2, band-local: wave w's 16 edges x all 64 out-channels ----
    const s16x8 af0 = *(const s16x8*)&X2[(16 * w + r) * SX2 + 8 * g];
    const s16x8 af1 = *(const s16x8*)&X2[(16 * w + r) * SX2 + 32 + 8 * g];
    f32x4 acc2[4];
#pragma unroll
    for (int nb = 0; nb < 4; ++nb)
      acc2[nb] = (f32x4){b2v[nb], b2v[nb], b2v[nb], b2v[nb]};
#pragma unroll
    for (int nb = 0; nb < 4; ++nb) {
      const s16x8 bf0 = *(const s16x8*)&W2L[(size_t)((0 + g) * 64 + nb * 16 + r) * 8];
      const s16x8 bf1 = *(const s16x8*)&W2L[(size_t)((4 + g) * 64 + nb * 16 + r) * 8];
      acc2[nb] = __builtin_amdgcn_mfma_f32_16x16x32_bf16(af0, bf0, acc2[nb], 0, 0, 0);
      acc2[nb] = __builtin_amdgcn_mfma_f32_16x16x32_bf16(af1, bf1, acc2[nb], 0, 0, 0);
    }

    // ---- messages -> X2, OWN band only (rows 16w..16w+15) ----
#pragma unroll
    for (int nb = 0; nb < 4; ++nb)
#pragma unroll
      for (int i = 0; i < 4; ++i)
        X2[(16 * w + 4 * g + i) * SX2 + nb * 16 + r] = f2bf(acc2[nb][i]);
    asm volatile("s_waitcnt lgkmcnt(0)" ::: "memory");   // own writes retired
    __builtin_amdgcn_sched_barrier(0);

    // ---- segmented reduce over own band (NO barrier needed) ----
    {
      float sum = 0.0f;
      int curt = -1;
#pragma unroll 4
      for (int i = 0; i < 16; ++i) {
        const int rr = 16 * w + i;
        const int tt = tgts[t & 1][rr];              // wave-uniform
        const float v = bf2f(X2[rr * SX2 + lane]);
        if (tt != curt) {
          if (curt >= 0) atomicAdd(agg + (size_t)curt * 64 + lane, sum);
          curt = tt;
          sum = 0.0f;
        }
        if (tt >= 0) sum += v;
      }
      if (curt >= 0) atomicAdd(agg + (size_t)curt * 64 + lane, sum);
    }
    // next iteration's barrier A orders reduce reads vs next relu writes
  }
}

// ---------------- node MLP (MFMA) ----------------
__global__ __launch_bounds__(256, 4)
void node_mlp_mfma(const unsigned short* __restrict__ hb, const float* __restrict__ agg,
                   const unsigned short* __restrict__ w1p, const float* __restrict__ b1,
                   const unsigned short* __restrict__ w2p, const float* __restrict__ b2,
                   float* __restrict__ out, int N) {
  __shared__ unsigned short X[64 * SXN];
  __shared__ unsigned short X2[64 * SX2];

  const int tid = threadIdx.x;
  const int w = tid >> 6, lane = tid & 63;
  const int g = lane >> 4, r = lane & 15;
  const long long base = (long long)blockIdx.x * 64;

  {
    const int row = tid >> 2, q = tid & 3;
    long long n = base + row;
    if (n >= N) n = N - 1;
    const u16x8* hr = (const u16x8*)(hb + (size_t)n * 64);
    *(u16x8*)&X[row * SXN + 16 * q] = hr[2 * q];
    *(u16x8*)&X[row * SXN + 16 * q + 8] = hr[2 * q + 1];
    const float4* ar = (const float4*)(agg + (size_t)n * 64);
    *(u16x8*)&X[row * SXN + 64 + 16 * q] = pack8(ar[4 * q], ar[4 * q + 1]);
    *(u16x8*)&X[row * SXN + 64 + 16 * q + 8] = pack8(ar[4 * q + 2], ar[4 * q + 3]);
  }
  __syncthreads();

  const int cb = w * 16;

  const float bias1 = b1[cb + r];
  f32x4 acc[4];
  acc[0] = acc[1] = acc[2] = acc[3] = (f32x4){bias1, bias1, bias1, bias1};
#pragma unroll
  for (int kk = 0; kk < 4; ++kk) {
    const s16x8 bf = *(const s16x8*)(w1p + (size_t)((kk * 4 + g) * 64 + cb + r) * 8);
#pragma unroll
    for (int er = 0; er < 4; ++er) {
      const s16x8 af = *(const s16x8*)&X[(er * 16 + r) * SXN + kk * 32 + 8 * g];
      acc[er] = __builtin_amdgcn_mfma_f32_16x16x32_bf16(af, bf, acc[er], 0, 0, 0);
    }
  }

#pragma unroll
  for (int er = 0; er < 4; ++er)
#pragma unroll
    for (int i = 0; i < 4; ++i)
      X2[(er * 16 + 4 * g + i) * SX2 + cb + r] = f2bf(fmaxf(acc[er][i], 0.0f));
  __syncthreads();

  const float bias2 = b2[cb + r];
  f32x4 a2[4];
  a2[0] = a2[1] = a2[2] = a2[3] = (f32x4){bias2, bias2, bias2, bias2};
#pragma unroll
  for (int kk = 0; kk < 2; ++kk) {
    const s16x8 bf = *(const s16x8*)(w2p + (size_t)((kk * 4 + g) * 64 + cb + r) * 8);
#pragma unroll
    for (int er = 0; er < 4; ++er) {
      const s16x8 af = *(const s16x8*)&X2[(er * 16 + r) * SX2 + kk * 32 + 8 * g];
      a2[er] = __builtin_amdgcn_mfma_f32_16x16x32_bf16(af, bf, a2[er], 0, 0, 0);
    }
  }

#pragma unroll
  for (int er = 0; er < 4; ++er)
#pragma unroll
    for (int i = 0; i < 4; ++i) {
      const long long n = base + er * 16 + 4 * g + i;
      if (n < N) out[n * 64 + cb + r] = a2[er][i];
    }
}

// ---------------- host ----------------
extern "C" void kernel_launch(void* const* d_in, const int* in_sizes, int n_in,
                              void* d_out, int out_size, void* d_ws, size_t ws_size,
                              hipStream_t stream) {
  const float* h   = (const float*)d_in[0];
  const int*   ei  = (const int*)d_in[1];
  const float* ef  = (const float*)d_in[2];
  const float* eW1 = (const float*)d_in[3];
  const float* eb1 = (const float*)d_in[4];
  const float* eW2 = (const float*)d_in[5];
  const float* eb2 = (const float*)d_in[6];
  const float* uW1 = (const float*)d_in[7];
  const float* ub1 = (const float*)d_in[8];
  const float* uW2 = (const float*)d_in[9];
  const float* ub2 = (const float*)d_in[10];
  float* out = (float*)d_out;

  const int N = in_sizes[0] / 64;   // 100000
  const int E = in_sizes[1] / 2;    // 1600000
  const int nchunks = (N + SCAN_CHUNK - 1) / SCAN_CHUNK;
  const int ntiles = (E + 63) / 64;
  const int nblk = ntiles < NBLK_EDGE ? ntiles : NBLK_EDGE;
  const int tpb = (ntiles + nblk - 1) / nblk;

  size_t off = 0;
  auto alloc = [&](size_t bytes) { size_t o = off; off += (bytes + 255) & ~(size_t)255; return o; };
  const size_t agg_off    = alloc((size_t)N * 64 * 4);   // 25.6 MB (atomic target)
  const size_t deg_off    = alloc((size_t)N * 4);        // adjacent: single memset
  const size_t hb_off     = alloc((size_t)N * 64 * 2);
  const size_t w1p_off    = alloc((size_t)160 * 64 * 2);
  const size_t w2p_off    = alloc((size_t)64 * 64 * 2);
  const size_t uw1p_off   = alloc((size_t)128 * 64 * 2);
  const size_t uw2p_off   = alloc((size_t)64 * 64 * 2);
  const size_t aoe_off    = alloc((size_t)E * 16);       // 25.6 MB AoS {s,t,e,0}
  const size_t start_off  = alloc((size_t)N * 4);
  const size_t cursor_off = alloc((size_t)N * 4);
  const size_t csum_off   = alloc((size_t)nchunks * 4);
  const size_t coff_off   = alloc((size_t)nchunks * 4);
  char* ws = (char*)d_ws;

  float*          agg  = (float*)(ws + agg_off);
  int*            deg  = (int*)(ws + deg_off);
  unsigned short* hb   = (unsigned short*)(ws + hb_off);
  unsigned short* w1p  = (unsigned short*)(ws + w1p_off);
  unsigned short* w2p  = (unsigned short*)(ws + w2p_off);
  unsigned short* uw1p = (unsigned short*)(ws + uw1p_off);
  unsigned short* uw2p = (unsigned short*)(ws + uw2p_off);
  int4* aoe   = (int4*)(ws + aoe_off);
  int* start  = (int*)(ws + start_off);
  int* cursor = (int*)(ws + cursor_off);
  int* csum   = (int*)(ws + csum_off);
  int* coff   = (int*)(ws + coff_off);

  hipMemsetAsync(ws + agg_off, 0, deg_off + (size_t)N * 4 - agg_off, stream);

  const long long htot = (long long)N * 64;
  const int conv_blocks = (int)((htot / 4 + 255) / 256);
  prep<<<conv_blocks + 13 + 1024, 256, 0, stream>>>(h, hb, htot, eW1, eW2, uW1, uW2,
                                                    w1p, w2p, uw1p, uw2p, ei, deg, E,
                                                    conv_blocks);

  scan_chunks<<<nchunks, 256, 0, stream>>>(deg, start, csum, N);
  scan_sums<<<1, 256, 0, stream>>>(csum, coff, nchunks);
  add_offsets<<<(N + 255) / 256, 256, 0, stream>>>(start, coff, cursor, N);
  fill_elist<<<1024, 256, 0, stream>>>(ei, cursor, aoe, E);

  edge_mlp_fused<<<nblk, 256, 0, stream>>>(hb, ef, w1p, eb1, w2p, eb2, aoe, agg, E, ntiles, tpb);
  node_mlp_mfma<<<(N + 63) / 64, 256, 0, stream>>>(hb, agg, uw1p, ub1, uw2p, ub2, out, N);
}